// Round 4
// baseline (273.437 us; speedup 1.0000x reference)
//
#include <hip/hip_runtime.h>

#define D_ 1024
#define H_ 16
#define DH_ 64
#define S_ 2048
#define B_ 4
#define N_ (B_*S_)    // 8192 tokens
#define M3_ 3072
// SCALE * log2(e): fold into q so softmax uses exp2 directly
#define QSC_ 0.18033688011112042f

typedef _Float16 f16;
typedef _Float16 f16x8 __attribute__((ext_vector_type(8)));
typedef _Float16 f16x4 __attribute__((ext_vector_type(4)));
typedef _Float16 f16x2 __attribute__((ext_vector_type(2)));
typedef __fp16   h16x2 __attribute__((ext_vector_type(2)));
typedef float    f32x4 __attribute__((ext_vector_type(4)));

typedef __attribute__((address_space(1))) void gvoid;
typedef __attribute__((address_space(3))) void lvoid;

__device__ __forceinline__ void gl16(const f16* g, f16* l) {
    __builtin_amdgcn_global_load_lds((gvoid*)g, (lvoid*)l, 16, 0, 0);
}

__device__ __forceinline__ f16x2 pk_cvt(float a, float b) {
#if __has_builtin(__builtin_amdgcn_cvt_pkrtz)
    h16x2 t = __builtin_amdgcn_cvt_pkrtz(a, b);
    return __builtin_bit_cast(f16x2, t);
#else
    f16x2 r; r[0] = (f16)a; r[1] = (f16)b; return r;
#endif
}

// ---------------------------------------------------------------- cvt x -> fp16
__global__ __launch_bounds__(256) void cvt_x_kernel(const float* __restrict__ in,
                                                    f16* __restrict__ out) {
    size_t i = ((size_t)blockIdx.x * 256 + threadIdx.x) * 4;
    float4 f = *reinterpret_cast<const float4*>(in + i);
    f16x4 o;
    o[0] = (f16)f.x; o[1] = (f16)f.y; o[2] = (f16)f.z; o[3] = (f16)f.w;
    *reinterpret_cast<f16x4*>(out + i) = o;
}

// ------------------------------------------- weight transpose + convert to fp16
// in: [K][Nc] fp32  ->  out: [Nc][K] fp16
__global__ __launch_bounds__(256) void wt_cvt_kernel(const float* __restrict__ in,
                                                     f16* __restrict__ out,
                                                     int K, int Nc) {
    __shared__ float tile[32][33];
    int tx = threadIdx.x & 31, ty = threadIdx.x >> 5;
    int c = blockIdx.x * 32 + tx;
    #pragma unroll
    for (int i = 0; i < 4; i++) {
        int r = blockIdx.y * 32 + ty + i * 8;
        tile[ty + i * 8][tx] = in[(size_t)r * Nc + c];
    }
    __syncthreads();
    #pragma unroll
    for (int i = 0; i < 4; i++) {
        int r2 = blockIdx.x * 32 + ty + i * 8;   // out row (col of in)
        int c2 = blockIdx.y * 32 + tx;           // out col (row of in)
        out[(size_t)r2 * K + c2] = (f16)tile[tx][ty + i * 8];
    }
}

// --------------------------------------------------------------- QKV GEMM
// C[n][m] = sum_k A[n][k]*Bt[m][k] + bias[m]; scatter q/k -> [b][h][s][d],
// V fused-transposed -> vT [b][h][d][s] (packed f16x4 along s).
// q pre-scaled by QSC_ (attn softmax runs in exp2 domain)
__global__ __launch_bounds__(256) void gemm_qkv_kernel(
        const f16* __restrict__ A, const f16* __restrict__ Bt,
        const float* __restrict__ bias,
        f16* __restrict__ qo, f16* __restrict__ ko, f16* __restrict__ vTo) {
    __shared__ __align__(16) f16 As[128 * 32];
    __shared__ __align__(16) f16 Bs[128 * 32];
    const int tid  = threadIdx.x;
    const int lane = tid & 63, w = tid >> 6;
    const int quad = lane >> 4, lrow = lane & 15;
    const int wm = (w & 1) * 64, wn = (w >> 1) * 64;
    const int n0 = blockIdx.x * 128, m0 = blockIdx.y * 128;

    f32x4 acc[4][4];
    #pragma unroll
    for (int i = 0; i < 4; i++)
        #pragma unroll
        for (int j = 0; j < 4; j++) acc[i][j] = {0.f, 0.f, 0.f, 0.f};

    const int ar0 = tid >> 2, ap0 = tid & 3;
    const f16* Ag0 = A  + (size_t)(n0 + ar0) * D_ + ap0 * 8;
    const f16* Ag1 = Ag0 + (size_t)64 * D_;
    const f16* Bg0 = Bt + (size_t)(m0 + ar0) * D_ + ap0 * 8;
    const f16* Bg1 = Bg0 + (size_t)64 * D_;
    f16* Asl = As + tid * 8;
    f16* Bsl = Bs + tid * 8;

    for (int kt = 0; kt < D_ / 32; kt++) {
        gl16(Ag0 + kt * 32, Asl);
        gl16(Ag1 + kt * 32, Asl + 64 * 32);
        gl16(Bg0 + kt * 32, Bsl);
        gl16(Bg1 + kt * 32, Bsl + 64 * 32);
        __syncthreads();
        f16x8 af[4], bf[4];
        #pragma unroll
        for (int i = 0; i < 4; i++)
            af[i] = *reinterpret_cast<const f16x8*>(&As[(wm + i * 16 + lrow) * 32 + quad * 8]);
        #pragma unroll
        for (int j = 0; j < 4; j++)
            bf[j] = *reinterpret_cast<const f16x8*>(&Bs[(wn + j * 16 + lrow) * 32 + quad * 8]);
        #pragma unroll
        for (int i = 0; i < 4; i++)
            #pragma unroll
            for (int j = 0; j < 4; j++)
                acc[i][j] = __builtin_amdgcn_mfma_f32_16x16x32_f16(af[i], bf[j], acc[i][j], 0, 0, 0);
        __syncthreads();
    }

    // epilogue: bias + route. q/k: [b][h][s][d]; v: [b][h][d][s] packed x4
    #pragma unroll
    for (int j = 0; j < 4; j++) {
        int m   = m0 + wn + j * 16 + lrow;
        int sec = m >> 10;
        int hd  = m & 1023;
        int hh  = hd >> 6, d = hd & 63;
        float bb = bias[m];
        if (sec == 2) {
            #pragma unroll
            for (int i = 0; i < 4; i++) {
                int n = n0 + wm + i * 16 + quad * 4;   // r=0 element
                int bidx = n >> 11, s = n & 2047;
                f16x4 o;
                #pragma unroll
                for (int r = 0; r < 4; r++) o[r] = (f16)(acc[i][j][r] + bb);
                *reinterpret_cast<f16x4*>(
                    &vTo[(((size_t)(bidx * H_ + hh)) * DH_ + d) * S_ + s]) = o;
            }
        } else {
            f16* dst = (sec == 0) ? qo : ko;
            float sc = (sec == 0) ? QSC_ : 1.0f;
            #pragma unroll
            for (int i = 0; i < 4; i++) {
                #pragma unroll
                for (int r = 0; r < 4; r++) {
                    int n = n0 + wm + i * 16 + quad * 4 + r;
                    int bidx = n >> 11, s = n & 2047;
                    dst[(((size_t)(bidx * H_ + hh)) * S_ + s) * DH_ + d] =
                        (f16)((acc[i][j][r] + bb) * sc);
                }
            }
        }
    }
}

// --------------------------------------------------------------- flash attention
// v6: v5 + T3/T4 — triple-buffered K/V, counted vmcnt, raw s_barrier.
//  - 3 LDS buffers (48 KiB) -> 2 tiles of gl16s in flight. At tile kt we issue
//    kt+2's loads, compute kt, then wait vmcnt(4) (kt+1 landed; kt+2 STAYS in
//    flight across the barrier) -> the wait covers loads issued a full tile
//    (~800 cyc) earlier instead of draining loads issued ~1 phase earlier.
//    Main loop never drains vmcnt to 0 (T4).
//  - launch_bounds(256,3): 3 blocks/CU (12 waves/CU ~= measured avg before,
//    but stalls shrink).
//  - Intra-tile pipeline + setprio from v5 unchanged.
// q,k: [bh][s][64] (q pre-scaled by QSC_); vT: [bh][64][s]; ctx: [b*S][1024] f16
__global__ __launch_bounds__(256, 3) void attn_kernel(
        const f16* __restrict__ q, const f16* __restrict__ k,
        const f16* __restrict__ vT, f16* __restrict__ ctx) {
    __shared__ __align__(16) f16 Ks[3][64 * 64];   // [slot][d], swizzled parts
    __shared__ __align__(16) f16 Vs[3][64 * 64];   // [d][kv],  swizzled parts
    const int tid  = threadIdx.x;
    const int lane = tid & 63, w = tid >> 6;
    const int quad = lane >> 4, lrow = lane & 15;
    const int id = blockIdx.x;
    const int bh = id & 63;                  // id%8 == bh%8 -> same XCD per head
    const int q0 = (id >> 6) * 128;          // 128 q rows per block, 32 per wave
    const int b  = bh >> 4, h = bh & 15;
    const f16* qb = q  + (size_t)bh * S_ * DH_;
    const f16* kb = k  + (size_t)bh * S_ * DH_;
    const f16* vb = vT + (size_t)bh * DH_ * S_;

    // Q fragments (B-operand: n=lane&15 -> q, k=quad*8+j -> d); 2 frags/wave
    f16x8 qf[2][2];
    #pragma unroll
    for (int f = 0; f < 2; f++)
        #pragma unroll
        for (int hf = 0; hf < 2; hf++)
            qf[f][hf] = *reinterpret_cast<const f16x8*>(
                qb + (size_t)(q0 + w * 32 + f * 16 + lrow) * DH_ + hf * 32 + quad * 8);

    // ones fragment for l-accumulation MFMA (A[m][k] = 1)
    f16x8 ones8;
    #pragma unroll
    for (int i = 0; i < 8; i++) ones8[i] = (f16)1.f;

    f32x4 lacc[2];    // all 16 C-rows hold the same full kv-sum per q-col
    f32x4 ot[2][4];   // O^T accum: col=lane&15 -> q, row=dj*16+quad*4+r -> d
    #pragma unroll
    for (int f = 0; f < 2; f++) {
        lacc[f] = {0.f, 0.f, 0.f, 0.f};
        #pragma unroll
        for (int dj = 0; dj < 4; dj++) ot[f][dj] = {0.f, 0.f, 0.f, 0.f};
    }

    // K gl16 source offsets: chunk c -> LDS slot s=c>>3, 16B part p=c&7.
    // Stored data = K[ sigma^{-1}(s) ][ (p ^ (s&7))*8 .. +8 ).
    // sigma^{-1}: s -> (s&~31) | (((s>>2)&3)<<3) | (((s>>4)&1)<<2) | (s&3)
    // V gl16 source offsets: chunk c -> LDS row d=c>>3, part p=c&7 stores
    // kv-part p^(d&7) of global row d.
    int koff[2], voff[2];
    #pragma unroll
    for (int i = 0; i < 2; i++) {
        int c = i * 256 + tid;
        int s = c >> 3, p = c & 7;
        int g = (s & ~31) | (((s >> 2) & 3) << 3) | (((s >> 4) & 1) << 2) | (s & 3);
        koff[i] = g * DH_ + ((p ^ (s & 7)) * 8);
        voff[i] = s * S_ + ((p ^ (s & 7)) * 8);   // for V: s is the d-row
    }

    // prologue: stage tile 0 -> buf0, tile 1 -> buf1 (8 gl16s outstanding),
    // wait for tile 0 only (vmcnt(4)), tile 1 stays in flight.
    #pragma unroll
    for (int i = 0; i < 2; i++) {
        gl16(kb + koff[i], &Ks[0][(i * 256 + tid) * 8]);
        gl16(vb + voff[i], &Vs[0][(i * 256 + tid) * 8]);
    }
    #pragma unroll
    for (int i = 0; i < 2; i++) {
        gl16(kb + (size_t)64 * DH_ + koff[i], &Ks[1][(i * 256 + tid) * 8]);
        gl16(vb + 64 + voff[i],               &Vs[1][(i * 256 + tid) * 8]);
    }
    asm volatile("s_waitcnt vmcnt(4)" ::: "memory");
    __builtin_amdgcn_s_barrier();

    // read-side XOR chunk offsets (elements) for K
    const int xr0 = (quad ^ (lrow & 7)) * 8;          // d-part quad
    const int xr1 = ((quad + 4) ^ (lrow & 7)) * 8;    // d-part quad+4

    union PU { f16x8 v; f16x2 w[4]; };

    const int NT = S_ / 64;
    int cur = 0;
    for (int kt = 0; kt < NT; kt++) {
        const f16* Kc = Ks[cur];
        const f16* Vc = Vs[cur];

        // ---- issue tile kt+2 staging into buffer (cur+2)%3 (tile kt-1's,
        //      released by the barrier at end of tile kt-1)
        if (kt + 2 < NT) {
            int b2 = cur + 2; if (b2 >= 3) b2 -= 3;
            const size_t kv2 = (size_t)(kt + 2) * 64;
            #pragma unroll
            for (int i = 0; i < 2; i++) {
                gl16(kb + kv2 * DH_ + koff[i], &Ks[b2][(i * 256 + tid) * 8]);
                gl16(vb + kv2 + voff[i],       &Vs[b2][(i * 256 + tid) * 8]);
            }
            __builtin_amdgcn_sched_barrier(0);   // pin issue point
        }

        // ---- QK strips 0,1 (t=0)
        f32x4 st0[2][2];
        __builtin_amdgcn_s_setprio(1);
        #pragma unroll
        for (int half = 0; half < 2; half++) {
            const int rb = (half * 16 + lrow) * 64;
            const f16x8 k0 = *reinterpret_cast<const f16x8*>(&Kc[rb + xr0]);
            const f16x8 k1 = *reinterpret_cast<const f16x8*>(&Kc[rb + xr1]);
            #pragma unroll
            for (int f = 0; f < 2; f++) {
                f32x4 s = {0.f, 0.f, 0.f, 0.f};
                s = __builtin_amdgcn_mfma_f32_16x16x32_f16(k0, qf[f][0], s, 0, 0, 0);
                s = __builtin_amdgcn_mfma_f32_16x16x32_f16(k1, qf[f][1], s, 0, 0, 0);
                st0[half][f] = s;
            }
        }
        __builtin_amdgcn_s_setprio(0);

        // ---- exp + pack t=0
        PU p0[2];
        #pragma unroll
        for (int half = 0; half < 2; half++)
            #pragma unroll
            for (int f = 0; f < 2; f++) {
                f16x2 lo = pk_cvt(__builtin_amdgcn_exp2f(st0[half][f][0]),
                                  __builtin_amdgcn_exp2f(st0[half][f][1]));
                f16x2 hi = pk_cvt(__builtin_amdgcn_exp2f(st0[half][f][2]),
                                  __builtin_amdgcn_exp2f(st0[half][f][3]));
                p0[f].w[half * 2 + 0] = lo;
                p0[f].w[half * 2 + 1] = hi;
            }

        // ---- QK strips 2,3 (t=1) — bridges exp(t0)->PV(t0) dependency gap
        f32x4 st1[2][2];
        __builtin_amdgcn_s_setprio(1);
        #pragma unroll
        for (int half = 0; half < 2; half++) {
            const int rb = ((2 + half) * 16 + lrow) * 64;
            const f16x8 k0 = *reinterpret_cast<const f16x8*>(&Kc[rb + xr0]);
            const f16x8 k1 = *reinterpret_cast<const f16x8*>(&Kc[rb + xr1]);
            #pragma unroll
            for (int f = 0; f < 2; f++) {
                f32x4 s = {0.f, 0.f, 0.f, 0.f};
                s = __builtin_amdgcn_mfma_f32_16x16x32_f16(k0, qf[f][0], s, 0, 0, 0);
                s = __builtin_amdgcn_mfma_f32_16x16x32_f16(k1, qf[f][1], s, 0, 0, 0);
                st1[half][f] = s;
            }
        }
        __builtin_amdgcn_s_setprio(0);

        // ---- V fragments t=0
        f16x8 vf0[4];
        #pragma unroll
        for (int dj = 0; dj < 4; dj++)
            vf0[dj] = *reinterpret_cast<const f16x8*>(
                &Vc[(dj * 16 + lrow) * 64 + ((quad ^ (lrow & 7)) * 8)]);

        // ---- PV t=0 + lacc0
        __builtin_amdgcn_s_setprio(1);
        #pragma unroll
        for (int dj = 0; dj < 4; dj++)
            #pragma unroll
            for (int f = 0; f < 2; f++)
                ot[f][dj] = __builtin_amdgcn_mfma_f32_16x16x32_f16(vf0[dj], p0[f].v, ot[f][dj], 0, 0, 0);
        #pragma unroll
        for (int f = 0; f < 2; f++)
            lacc[f] = __builtin_amdgcn_mfma_f32_16x16x32_f16(ones8, p0[f].v, lacc[f], 0, 0, 0);
        __builtin_amdgcn_s_setprio(0);

        // ---- exp + pack t=1
        PU p1[2];
        #pragma unroll
        for (int half = 0; half < 2; half++)
            #pragma unroll
            for (int f = 0; f < 2; f++) {
                f16x2 lo = pk_cvt(__builtin_amdgcn_exp2f(st1[half][f][0]),
                                  __builtin_amdgcn_exp2f(st1[half][f][1]));
                f16x2 hi = pk_cvt(__builtin_amdgcn_exp2f(st1[half][f][2]),
                                  __builtin_amdgcn_exp2f(st1[half][f][3]));
                p1[f].w[half * 2 + 0] = lo;
                p1[f].w[half * 2 + 1] = hi;
            }

        // ---- V fragments t=1
        f16x8 vf1[4];
        #pragma unroll
        for (int dj = 0; dj < 4; dj++)
            vf1[dj] = *reinterpret_cast<const f16x8*>(
                &Vc[(dj * 16 + lrow) * 64 + (((4 + quad) ^ (lrow & 7)) * 8)]);

        // ---- PV t=1 + lacc1
        __builtin_amdgcn_s_setprio(1);
        #pragma unroll
        for (int dj = 0; dj < 4; dj++)
            #pragma unroll
            for (int f = 0; f < 2; f++)
                ot[f][dj] = __builtin_amdgcn_mfma_f32_16x16x32_f16(vf1[dj], p1[f].v, ot[f][dj], 0, 0, 0);
        #pragma unroll
        for (int f = 0; f < 2; f++)
            lacc[f] = __builtin_amdgcn_mfma_f32_16x16x32_f16(ones8, p1[f].v, lacc[f], 0, 0, 0);
        __builtin_amdgcn_s_setprio(0);

        // ---- end of tile: wait for tile kt+1's loads ONLY (kt+2 stays in
        //      flight across the barrier — T4), then barrier.
        if (kt + 2 < NT) {
            asm volatile("s_waitcnt vmcnt(4)" ::: "memory");
            __builtin_amdgcn_s_barrier();
        } else if (kt + 1 < NT) {
            asm volatile("s_waitcnt vmcnt(0)" ::: "memory");
            __builtin_amdgcn_s_barrier();
        }
        cur += 1; if (cur == 3) cur = 0;
    }

    #pragma unroll
    for (int f = 0; f < 2; f++) {
        float inv = 1.0f / lacc[f][0];
        int qrow = q0 + w * 32 + f * 16 + lrow;
        #pragma unroll
        for (int dj = 0; dj < 4; dj++) {
            f16x4 o;
            #pragma unroll
            for (int r = 0; r < 4; r++) o[r] = (f16)(ot[f][dj][r] * inv);
            *reinterpret_cast<f16x4*>(
                &ctx[((size_t)(b * S_ + qrow)) * D_ + h * DH_ + dj * 16 + quad * 4]) = o;
        }
    }
}

// --------------------------------------------------------------- output GEMM
// out[n][m] = sum_k ctx[n][k]*Bt[m][k] + bias[m]   (fp32 out)
__global__ __launch_bounds__(256) void gemm_out_kernel(
        const f16* __restrict__ A, const f16* __restrict__ Bt,
        const float* __restrict__ bias, float* __restrict__ out) {
    __shared__ __align__(16) f16 As[128 * 32];
    __shared__ __align__(16) f16 Bs[128 * 32];
    const int tid  = threadIdx.x;
    const int lane = tid & 63, w = tid >> 6;
    const int quad = lane >> 4, lrow = lane & 15;
    const int wm = (w & 1) * 64, wn = (w >> 1) * 64;
    const int n0 = blockIdx.x * 128, m0 = blockIdx.y * 128;

    f32x4 acc[4][4];
    #pragma unroll
    for (int i = 0; i < 4; i++)
        #pragma unroll
        for (int j = 0; j < 4; j++) acc[i][j] = {0.f, 0.f, 0.f, 0.f};

    const int ar0 = tid >> 2, ap0 = tid & 3;
    const f16* Ag0 = A  + (size_t)(n0 + ar0) * D_ + ap0 * 8;
    const f16* Ag1 = Ag0 + (size_t)64 * D_;
    const f16* Bg0 = Bt + (size_t)(m0 + ar0) * D_ + ap0 * 8;
    const f16* Bg1 = Bg0 + (size_t)64 * D_;
    f16* Asl = As + tid * 8;
    f16* Bsl = Bs + tid * 8;

    for (int kt = 0; kt < D_ / 32; kt++) {
        gl16(Ag0 + kt * 32, Asl);
        gl16(Ag1 + kt * 32, Asl + 64 * 32);
        gl16(Bg0 + kt * 32, Bsl);
        gl16(Bg1 + kt * 32, Bsl + 64 * 32);
        __syncthreads();
        f16x8 af[4], bf[4];
        #pragma unroll
        for (int i = 0; i < 4; i++)
            af[i] = *reinterpret_cast<const f16x8*>(&As[(wm + i * 16 + lrow) * 32 + quad * 8]);
        #pragma unroll
        for (int j = 0; j < 4; j++)
            bf[j] = *reinterpret_cast<const f16x8*>(&Bs[(wn + j * 16 + lrow) * 32 + quad * 8]);
        #pragma unroll
        for (int i = 0; i < 4; i++)
            #pragma unroll
            for (int j = 0; j < 4; j++)
                acc[i][j] = __builtin_amdgcn_mfma_f32_16x16x32_f16(af[i], bf[j], acc[i][j], 0, 0, 0);
        __syncthreads();
    }

    #pragma unroll
    for (int j = 0; j < 4; j++) {
        int m = m0 + wn + j * 16 + lrow;
        float bb = bias[m];
        #pragma unroll
        for (int i = 0; i < 4; i++)
            #pragma unroll
            for (int r = 0; r < 4; r++) {
                int n = n0 + wm + i * 16 + quad * 4 + r;
                out[(size_t)n * D_ + m] = acc[i][j][r] + bb;
            }
    }
}

// ------------------------------------------------------------------- launcher
extern "C" void kernel_launch(void* const* d_in, const int* in_sizes, int n_in,
                              void* d_out, int out_size, void* d_ws, size_t ws_size,
                              hipStream_t stream) {
    (void)in_sizes; (void)n_in; (void)out_size; (void)ws_size;
    const float* x     = (const float*)d_in[0];
    const float* w_qkv = (const float*)d_in[1];
    const float* b_qkv = (const float*)d_in[2];
    const float* w_out = (const float*)d_in[3];
    const float* b_out = (const float*)d_in[4];
    float* out = (float*)d_out;

    char* ws = (char*)d_ws;
    const size_t MB = 1024 * 1024;
    f16* xb    = (f16*)(ws);             // 16 MB  (reused as ctx after GEMM1)
    f16* wqkvT = (f16*)(ws + 16 * MB);   // 6 MB
    f16* woutT = (f16*)(ws + 22 * MB);   // 2 MB
    f16* qs    = (f16*)(ws + 24 * MB);   // 16 MB  [b][h][s][d], pre-scaled
    f16* kk    = (f16*)(ws + 40 * MB);   // 16 MB  [b][h][s][d]
    f16* vTb   = (f16*)(ws + 72 * MB);   // 16 MB  [b][h][d][s] (written by gemm_qkv)
    f16* ctx   = xb;                     // alias: xb dead after gemm_qkv

    cvt_x_kernel<<<(N_ * D_) / (256 * 4), 256, 0, stream>>>(x, xb);
    wt_cvt_kernel<<<dim3(M3_ / 32, D_ / 32), 256, 0, stream>>>(w_qkv, wqkvT, D_, M3_);
    wt_cvt_kernel<<<dim3(D_ / 32, D_ / 32), 256, 0, stream>>>(w_out, woutT, D_, D_);
    gemm_qkv_kernel<<<dim3(N_ / 128, M3_ / 128), 256, 0, stream>>>(xb, wqkvT, b_qkv, qs, kk, vTb);
    attn_kernel<<<(B_ * H_) * (S_ / 128), 256, 0, stream>>>(qs, kk, vTb, ctx);
    gemm_out_kernel<<<dim3(N_ / 128, D_ / 128), 256, 0, stream>>>(ctx, woutT, b_out, out);
}

// Round 5
// 272.207 us; speedup vs baseline: 1.0045x; 1.0045x over previous
//
#include <hip/hip_runtime.h>

#define D_ 1024
#define H_ 16
#define DH_ 64
#define S_ 2048
#define B_ 4
#define N_ (B_*S_)    // 8192 tokens
#define M3_ 3072
// SCALE * log2(e): fold into q so softmax uses exp2 directly
#define QSC_ 0.18033688011112042f

typedef _Float16 f16;
typedef _Float16 f16x8 __attribute__((ext_vector_type(8)));
typedef _Float16 f16x4 __attribute__((ext_vector_type(4)));
typedef _Float16 f16x2 __attribute__((ext_vector_type(2)));
typedef __fp16   h16x2 __attribute__((ext_vector_type(2)));
typedef float    f32x4 __attribute__((ext_vector_type(4)));

typedef __attribute__((address_space(1))) void gvoid;
typedef __attribute__((address_space(3))) void lvoid;

__device__ __forceinline__ void gl16(const f16* g, f16* l) {
    __builtin_amdgcn_global_load_lds((gvoid*)g, (lvoid*)l, 16, 0, 0);
}

__device__ __forceinline__ f16x2 pk_cvt(float a, float b) {
#if __has_builtin(__builtin_amdgcn_cvt_pkrtz)
    h16x2 t = __builtin_amdgcn_cvt_pkrtz(a, b);
    return __builtin_bit_cast(f16x2, t);
#else
    f16x2 r; r[0] = (f16)a; r[1] = (f16)b; return r;
#endif
}

// ---------------------------------------------------------------- cvt x -> fp16
__global__ __launch_bounds__(256) void cvt_x_kernel(const float* __restrict__ in,
                                                    f16* __restrict__ out) {
    size_t i = ((size_t)blockIdx.x * 256 + threadIdx.x) * 4;
    float4 f = *reinterpret_cast<const float4*>(in + i);
    f16x4 o;
    o[0] = (f16)f.x; o[1] = (f16)f.y; o[2] = (f16)f.z; o[3] = (f16)f.w;
    *reinterpret_cast<f16x4*>(out + i) = o;
}

// ------------------------------------------- weight transpose + convert to fp16
// in: [K][Nc] fp32  ->  out: [Nc][K] fp16
__global__ __launch_bounds__(256) void wt_cvt_kernel(const float* __restrict__ in,
                                                     f16* __restrict__ out,
                                                     int K, int Nc) {
    __shared__ float tile[32][33];
    int tx = threadIdx.x & 31, ty = threadIdx.x >> 5;
    int c = blockIdx.x * 32 + tx;
    #pragma unroll
    for (int i = 0; i < 4; i++) {
        int r = blockIdx.y * 32 + ty + i * 8;
        tile[ty + i * 8][tx] = in[(size_t)r * Nc + c];
    }
    __syncthreads();
    #pragma unroll
    for (int i = 0; i < 4; i++) {
        int r2 = blockIdx.x * 32 + ty + i * 8;   // out row (col of in)
        int c2 = blockIdx.y * 32 + tx;           // out col (row of in)
        out[(size_t)r2 * K + c2] = (f16)tile[tx][ty + i * 8];
    }
}

// --------------------------------------------------------------- QKV GEMM v2
// 256x256 tile, BK=64 split into 2 k-chunks of 32; 8 waves (2M x 4N), each wave
// owns 128x64 output (acc[8][4]). Double-buffered, K-CHUNK-granular staging via
// global_load_lds with counted vmcnt(4) across raw s_barriers (T3+T4): each
// phase {ds_read frags of chunk ck; issue next tile's chunk ck (4 gl16);
// 32 MFMA (setprio); vmcnt(4); s_barrier}. Steady state keeps 8 loads in
// flight and the wait only covers loads issued a full phase (~1240 cyc) ago —
// never drains to 0 in the main loop.
// LDS: static 128 KiB = [2 buf][4 rgn][8192 f16]; rgn 0/1 = A ck0/ck1,
// 2/3 = B ck0/ck1. XOR swizzle WITHIN a k-chunk: column pl of row r holds the
// row's original 16B part pl^(r&3) (2-bit XOR never crosses the chunk; with the
// 64B row stride the frag reads are bank-conflict-free, same model as attn's
// measured-zero pattern). Epilogue: verified q/k/v routing, i extended to 8.
__global__ __launch_bounds__(512, 2) void gemm_qkv_kernel(
        const f16* __restrict__ A, const f16* __restrict__ Bt,
        const float* __restrict__ bias,
        f16* __restrict__ qo, f16* __restrict__ ko, f16* __restrict__ vTo) {
    __shared__ __align__(16) f16 S[2 * 4 * 8192];   // 128 KiB
    const int tid  = threadIdx.x;
    const int lane = tid & 63, w = tid >> 6;
    const int quad = lane >> 4, lrow = lane & 15;
    const int G  = w >> 2;             // M-half (0/1)
    const int wn = (w & 3) * 64;       // N-quarter

    // XCD swizzle: 384 blocks = 8 XCDs x 48 consecutive tiles (384%8==0)
    const int id  = blockIdx.x;
    const int swz = (id & 7) * 48 + (id >> 3);
    const int n0 = (swz & 31) * 256;   // 32 M-blocks
    const int m0 = (swz >> 5) * 256;   // 12 N-blocks

    f32x4 acc[8][4];
    #pragma unroll
    for (int i = 0; i < 8; i++)
        #pragma unroll
        for (int j = 0; j < 4; j++) acc[i][j] = {0.f, 0.f, 0.f, 0.f};

    // staging: chunk c covers LDS 16B slot c of a region; row r=c>>2, col p=c&3.
    // column p stores original part p^(r&3) -> source offset below.
    const int c0 = tid, c1 = tid + 512;
    const int r0 = c0 >> 2, r1 = c1 >> 2;
    const int g0 = r0 * D_ + (((c0 & 3) ^ (r0 & 3)) * 8);
    const int g1 = r1 * D_ + (((c1 & 3) ^ (r1 & 3)) * 8);
    const f16* Ab = A  + (size_t)n0 * D_;
    const f16* Bb = Bt + (size_t)m0 * D_;

    // frag reads: original part quad of row r sits at column quad^(r&3);
    // r&3 == lrow&3 for all frag rows -> constant per-lane XOR.
    const int xq8   = (quad ^ (lrow & 3)) * 8;
    const int abase = (G * 128 + lrow) * 32 + xq8;   // + i*512
    const int bbase = (wn + lrow) * 32 + xq8;        // + j*512

#define STAGE_QKV(ktn, ck, nb) do {                                          \
    const int ko_ = (ktn) * 64 + (ck) * 32;                                  \
    gl16(Ab + ko_ + g0, &S[(((nb) * 4 + (ck)) * 8192) + c0 * 8]);            \
    gl16(Ab + ko_ + g1, &S[(((nb) * 4 + (ck)) * 8192) + c1 * 8]);            \
    gl16(Bb + ko_ + g0, &S[(((nb) * 4 + 2 + (ck)) * 8192) + c0 * 8]);        \
    gl16(Bb + ko_ + g1, &S[(((nb) * 4 + 2 + (ck)) * 8192) + c1 * 8]);        \
} while (0)

    // prologue: stage tile 0 chunk0 + chunk1 (8 loads); wait chunk0 only.
    STAGE_QKV(0, 0, 0);
    STAGE_QKV(0, 1, 0);
    asm volatile("s_waitcnt vmcnt(4)" ::: "memory");
    __builtin_amdgcn_s_barrier();
    __builtin_amdgcn_sched_barrier(0);

    #pragma unroll 1
    for (int kt = 0; kt < 15; kt++) {
        const int buf = kt & 1, nb = buf ^ 1;
        #pragma unroll
        for (int ck = 0; ck < 2; ck++) {
            const f16* Sa = &S[(buf * 4 + ck) * 8192];
            const f16* Sb = &S[(buf * 4 + 2 + ck) * 8192];
            f16x8 af[8], bf[4];
            #pragma unroll
            for (int i = 0; i < 8; i++)
                af[i] = *reinterpret_cast<const f16x8*>(Sa + abase + i * 512);
            #pragma unroll
            for (int j = 0; j < 4; j++)
                bf[j] = *reinterpret_cast<const f16x8*>(Sb + bbase + j * 512);
            STAGE_QKV(kt + 1, ck, nb);
            __builtin_amdgcn_sched_barrier(0);
            __builtin_amdgcn_s_setprio(1);
            #pragma unroll
            for (int i = 0; i < 8; i++)
                #pragma unroll
                for (int j = 0; j < 4; j++)
                    acc[i][j] = __builtin_amdgcn_mfma_f32_16x16x32_f16(af[i], bf[j], acc[i][j], 0, 0, 0);
            __builtin_amdgcn_s_setprio(0);
            // 8 outstanding (prev phase's 4 + this phase's 4): wait the old 4.
            asm volatile("s_waitcnt vmcnt(4)" ::: "memory");
            __builtin_amdgcn_s_barrier();
            __builtin_amdgcn_sched_barrier(0);
        }
    }
    // peeled tail kt = 15 (buf = 1): no staging; drain once between phases.
    {
        const int buf = 1;
        #pragma unroll
        for (int ck = 0; ck < 2; ck++) {
            const f16* Sa = &S[(buf * 4 + ck) * 8192];
            const f16* Sb = &S[(buf * 4 + 2 + ck) * 8192];
            f16x8 af[8], bf[4];
            #pragma unroll
            for (int i = 0; i < 8; i++)
                af[i] = *reinterpret_cast<const f16x8*>(Sa + abase + i * 512);
            #pragma unroll
            for (int j = 0; j < 4; j++)
                bf[j] = *reinterpret_cast<const f16x8*>(Sb + bbase + j * 512);
            __builtin_amdgcn_s_setprio(1);
            #pragma unroll
            for (int i = 0; i < 8; i++)
                #pragma unroll
                for (int j = 0; j < 4; j++)
                    acc[i][j] = __builtin_amdgcn_mfma_f32_16x16x32_f16(af[i], bf[j], acc[i][j], 0, 0, 0);
            __builtin_amdgcn_s_setprio(0);
            if (ck == 0) {
                asm volatile("s_waitcnt vmcnt(0)" ::: "memory");
                __builtin_amdgcn_s_barrier();
                __builtin_amdgcn_sched_barrier(0);
            }
        }
    }
#undef STAGE_QKV

    // epilogue: bias + route. q/k: [b][h][s][d]; v: [b][h][d][s] packed x4
    #pragma unroll
    for (int j = 0; j < 4; j++) {
        int m   = m0 + wn + j * 16 + lrow;
        int sec = m >> 10;
        int hd  = m & 1023;
        int hh  = hd >> 6, d = hd & 63;
        float bb = bias[m];
        if (sec == 2) {
            #pragma unroll
            for (int i = 0; i < 8; i++) {
                int n = n0 + G * 128 + i * 16 + quad * 4;   // r=0 element
                int bidx = n >> 11, s = n & 2047;
                f16x4 o;
                #pragma unroll
                for (int r = 0; r < 4; r++) o[r] = (f16)(acc[i][j][r] + bb);
                *reinterpret_cast<f16x4*>(
                    &vTo[(((size_t)(bidx * H_ + hh)) * DH_ + d) * S_ + s]) = o;
            }
        } else {
            f16* dst = (sec == 0) ? qo : ko;
            float sc = (sec == 0) ? QSC_ : 1.0f;
            #pragma unroll
            for (int i = 0; i < 8; i++) {
                #pragma unroll
                for (int r = 0; r < 4; r++) {
                    int n = n0 + G * 128 + i * 16 + quad * 4 + r;
                    int bidx = n >> 11, s = n & 2047;
                    dst[(((size_t)(bidx * H_ + hh)) * S_ + s) * DH_ + d] =
                        (f16)((acc[i][j][r] + bb) * sc);
                }
            }
        }
    }
}

// --------------------------------------------------------------- flash attention
// v5 (R3, 76.4us): 128 q rows/block, 64-KV tiles double-buffered via
// global_load_lds with source-side XOR swizzles (0 bank conflicts), 4 blocks/CU,
// intra-tile software pipeline + s_setprio. Reverted from the R4 3-buffer
// experiment (occupancy + L2-locality loss outweighed barrier-drain savings).
// q,k: [bh][s][64] (q pre-scaled by QSC_); vT: [bh][64][s]; ctx: [b*S][1024] f16
__global__ __launch_bounds__(256, 4) void attn_kernel(
        const f16* __restrict__ q, const f16* __restrict__ k,
        const f16* __restrict__ vT, f16* __restrict__ ctx) {
    __shared__ __align__(16) f16 Ks[2][64 * 64];   // [slot][d], swizzled parts
    __shared__ __align__(16) f16 Vs[2][64 * 64];   // [d][kv],  swizzled parts
    const int tid  = threadIdx.x;
    const int lane = tid & 63, w = tid >> 6;
    const int quad = lane >> 4, lrow = lane & 15;
    const int id = blockIdx.x;
    const int bh = id & 63;                  // id%8 == bh%8 -> same XCD per head
    const int q0 = (id >> 6) * 128;          // 128 q rows per block, 32 per wave
    const int b  = bh >> 4, h = bh & 15;
    const f16* qb = q  + (size_t)bh * S_ * DH_;
    const f16* kb = k  + (size_t)bh * S_ * DH_;
    const f16* vb = vT + (size_t)bh * DH_ * S_;

    // Q fragments (B-operand: n=lane&15 -> q, k=quad*8+j -> d); 2 frags/wave
    f16x8 qf[2][2];
    #pragma unroll
    for (int f = 0; f < 2; f++)
        #pragma unroll
        for (int hf = 0; hf < 2; hf++)
            qf[f][hf] = *reinterpret_cast<const f16x8*>(
                qb + (size_t)(q0 + w * 32 + f * 16 + lrow) * DH_ + hf * 32 + quad * 8);

    // ones fragment for l-accumulation MFMA (A[m][k] = 1)
    f16x8 ones8;
    #pragma unroll
    for (int i = 0; i < 8; i++) ones8[i] = (f16)1.f;

    f32x4 lacc[2];    // all 16 C-rows hold the same full kv-sum per q-col
    f32x4 ot[2][4];   // O^T accum: col=lane&15 -> q, row=dj*16+quad*4+r -> d
    #pragma unroll
    for (int f = 0; f < 2; f++) {
        lacc[f] = {0.f, 0.f, 0.f, 0.f};
        #pragma unroll
        for (int dj = 0; dj < 4; dj++) ot[f][dj] = {0.f, 0.f, 0.f, 0.f};
    }

    // K gl16 source offsets: chunk c -> LDS slot s=c>>3, 16B part p=c&7.
    // Stored data = K[ sigma^{-1}(s) ][ (p ^ (s&7))*8 .. +8 ).
    // sigma^{-1}: s -> (s&~31) | (((s>>2)&3)<<3) | (((s>>4)&1)<<2) | (s&3)
    // V gl16 source offsets: chunk c -> LDS row d=c>>3, part p=c&7 stores
    // kv-part p^(d&7) of global row d.
    int koff[2], voff[2];
    #pragma unroll
    for (int i = 0; i < 2; i++) {
        int c = i * 256 + tid;
        int s = c >> 3, p = c & 7;
        int g = (s & ~31) | (((s >> 2) & 3) << 3) | (((s >> 4) & 1) << 2) | (s & 3);
        koff[i] = g * DH_ + ((p ^ (s & 7)) * 8);
        voff[i] = s * S_ + ((p ^ (s & 7)) * 8);   // for V: s is the d-row
    }

    // stage tile 0 into buf 0
    #pragma unroll
    for (int i = 0; i < 2; i++) {
        gl16(kb + koff[i], &Ks[0][(i * 256 + tid) * 8]);
        gl16(vb + voff[i], &Vs[0][(i * 256 + tid) * 8]);
    }
    __syncthreads();

    // read-side XOR chunk offsets (elements) for K
    const int xr0 = (quad ^ (lrow & 7)) * 8;          // d-part quad
    const int xr1 = ((quad + 4) ^ (lrow & 7)) * 8;    // d-part quad+4

    union PU { f16x8 v; f16x2 w[4]; };

    const int NT = S_ / 64;
    for (int kt = 0; kt < NT; kt++) {
        const int cur = kt & 1;
        const f16* Kc = Ks[cur];
        const f16* Vc = Vs[cur];

        // ---- QK strips 0,1 (t=0)
        f32x4 st0[2][2];
        __builtin_amdgcn_s_setprio(1);
        #pragma unroll
        for (int half = 0; half < 2; half++) {
            const int rb = (half * 16 + lrow) * 64;
            const f16x8 k0 = *reinterpret_cast<const f16x8*>(&Kc[rb + xr0]);
            const f16x8 k1 = *reinterpret_cast<const f16x8*>(&Kc[rb + xr1]);
            #pragma unroll
            for (int f = 0; f < 2; f++) {
                f32x4 s = {0.f, 0.f, 0.f, 0.f};
                s = __builtin_amdgcn_mfma_f32_16x16x32_f16(k0, qf[f][0], s, 0, 0, 0);
                s = __builtin_amdgcn_mfma_f32_16x16x32_f16(k1, qf[f][1], s, 0, 0, 0);
                st0[half][f] = s;
            }
        }
        __builtin_amdgcn_s_setprio(0);

        // ---- issue next tile staging (lands during this tile's compute)
        if (kt + 1 < NT) {
            const size_t kv1 = (size_t)(kt + 1) * 64;
            #pragma unroll
            for (int i = 0; i < 2; i++) {
                gl16(kb + kv1 * DH_ + koff[i], &Ks[cur ^ 1][(i * 256 + tid) * 8]);
                gl16(vb + kv1 + voff[i],       &Vs[cur ^ 1][(i * 256 + tid) * 8]);
            }
        }

        // ---- exp + pack t=0
        PU p0[2];
        #pragma unroll
        for (int half = 0; half < 2; half++)
            #pragma unroll
            for (int f = 0; f < 2; f++) {
                f16x2 lo = pk_cvt(__builtin_amdgcn_exp2f(st0[half][f][0]),
                                  __builtin_amdgcn_exp2f(st0[half][f][1]));
                f16x2 hi = pk_cvt(__builtin_amdgcn_exp2f(st0[half][f][2]),
                                  __builtin_amdgcn_exp2f(st0[half][f][3]));
                p0[f].w[half * 2 + 0] = lo;
                p0[f].w[half * 2 + 1] = hi;
            }

        // ---- QK strips 2,3 (t=1) — bridges exp(t0)->PV(t0) dependency gap
        f32x4 st1[2][2];
        __builtin_amdgcn_s_setprio(1);
        #pragma unroll
        for (int half = 0; half < 2; half++) {
            const int rb = ((2 + half) * 16 + lrow) * 64;
            const f16x8 k0 = *reinterpret_cast<const f16x8*>(&Kc[rb + xr0]);
            const f16x8 k1 = *reinterpret_cast<const f16x8*>(&Kc[rb + xr1]);
            #pragma unroll
            for (int f = 0; f < 2; f++) {
                f32x4 s = {0.f, 0.f, 0.f, 0.f};
                s = __builtin_amdgcn_mfma_f32_16x16x32_f16(k0, qf[f][0], s, 0, 0, 0);
                s = __builtin_amdgcn_mfma_f32_16x16x32_f16(k1, qf[f][1], s, 0, 0, 0);
                st1[half][f] = s;
            }
        }
        __builtin_amdgcn_s_setprio(0);

        // ---- V fragments t=0
        f16x8 vf0[4];
        #pragma unroll
        for (int dj = 0; dj < 4; dj++)
            vf0[dj] = *reinterpret_cast<const f16x8*>(
                &Vc[(dj * 16 + lrow) * 64 + ((quad ^ (lrow & 7)) * 8)]);

        // ---- PV t=0 + lacc0
        __builtin_amdgcn_s_setprio(1);
        #pragma unroll
        for (int dj = 0; dj < 4; dj++)
            #pragma unroll
            for (int f = 0; f < 2; f++)
                ot[f][dj] = __builtin_amdgcn_mfma_f32_16x16x32_f16(vf0[dj], p0[f].v, ot[f][dj], 0, 0, 0);
        #pragma unroll
        for (int f = 0; f < 2; f++)
            lacc[f] = __builtin_amdgcn_mfma_f32_16x16x32_f16(ones8, p0[f].v, lacc[f], 0, 0, 0);
        __builtin_amdgcn_s_setprio(0);

        // ---- exp + pack t=1
        PU p1[2];
        #pragma unroll
        for (int half = 0; half < 2; half++)
            #pragma unroll
            for (int f = 0; f < 2; f++) {
                f16x2 lo = pk_cvt(__builtin_amdgcn_exp2f(st1[half][f][0]),
                                  __builtin_amdgcn_exp2f(st1[half][f][1]));
                f16x2 hi = pk_cvt(__builtin_amdgcn_exp2f(st1[half][f][2]),
                                  __builtin_amdgcn_exp2f(st1[half][f][3]));
                p1[f].w[half * 2 + 0] = lo;
                p1[f].w[half * 2 + 1] = hi;
            }

        // ---- V fragments t=1
        f16x8 vf1[4];
        #pragma unroll
        for (int dj = 0; dj < 4; dj++)
            vf1[dj] = *reinterpret_cast<const f16x8*>(
                &Vc[(dj * 16 + lrow) * 64 + (((4 + quad) ^ (lrow & 7)) * 8)]);

        // ---- PV t=1 + lacc1
        __builtin_amdgcn_s_setprio(1);
        #pragma unroll
        for (int dj = 0; dj < 4; dj++)
            #pragma unroll
            for (int f = 0; f < 2; f++)
                ot[f][dj] = __builtin_amdgcn_mfma_f32_16x16x32_f16(vf1[dj], p1[f].v, ot[f][dj], 0, 0, 0);
        #pragma unroll
        for (int f = 0; f < 2; f++)
            lacc[f] = __builtin_amdgcn_mfma_f32_16x16x32_f16(ones8, p1[f].v, lacc[f], 0, 0, 0);
        __builtin_amdgcn_s_setprio(0);

        __syncthreads();   // drains gl16 (vmcnt) -> next buffer ready
    }

    #pragma unroll
    for (int f = 0; f < 2; f++) {
        float inv = 1.0f / lacc[f][0];
        int qrow = q0 + w * 32 + f * 16 + lrow;
        #pragma unroll
        for (int dj = 0; dj < 4; dj++) {
            f16x4 o;
            #pragma unroll
            for (int r = 0; r < 4; r++) o[r] = (f16)(ot[f][dj][r] * inv);
            *reinterpret_cast<f16x4*>(
                &ctx[((size_t)(b * S_ + qrow)) * D_ + h * DH_ + dj * 16 + quad * 4]) = o;
        }
    }
}

// --------------------------------------------------------------- output GEMM
// out[n][m] = sum_k ctx[n][k]*Bt[m][k] + bias[m]   (fp32 out)
__global__ __launch_bounds__(256) void gemm_out_kernel(
        const f16* __restrict__ A, const f16* __restrict__ Bt,
        const float* __restrict__ bias, float* __restrict__ out) {
    __shared__ __align__(16) f16 As[128 * 32];
    __shared__ __align__(16) f16 Bs[128 * 32];
    const int tid  = threadIdx.x;
    const int lane = tid & 63, w = tid >> 6;
    const int quad = lane >> 4, lrow = lane & 15;
    const int wm = (w & 1) * 64, wn = (w >> 1) * 64;
    const int n0 = blockIdx.x * 128, m0 = blockIdx.y * 128;

    f32x4 acc[4][4];
    #pragma unroll
    for (int i = 0; i < 4; i++)
        #pragma unroll
        for (int j = 0; j < 4; j++) acc[i][j] = {0.f, 0.f, 0.f, 0.f};

    const int ar0 = tid >> 2, ap0 = tid & 3;
    const f16* Ag0 = A  + (size_t)(n0 + ar0) * D_ + ap0 * 8;
    const f16* Ag1 = Ag0 + (size_t)64 * D_;
    const f16* Bg0 = Bt + (size_t)(m0 + ar0) * D_ + ap0 * 8;
    const f16* Bg1 = Bg0 + (size_t)64 * D_;
    f16* Asl = As + tid * 8;
    f16* Bsl = Bs + tid * 8;

    for (int kt = 0; kt < D_ / 32; kt++) {
        gl16(Ag0 + kt * 32, Asl);
        gl16(Ag1 + kt * 32, Asl + 64 * 32);
        gl16(Bg0 + kt * 32, Bsl);
        gl16(Bg1 + kt * 32, Bsl + 64 * 32);
        __syncthreads();
        f16x8 af[4], bf[4];
        #pragma unroll
        for (int i = 0; i < 4; i++)
            af[i] = *reinterpret_cast<const f16x8*>(&As[(wm + i * 16 + lrow) * 32 + quad * 8]);
        #pragma unroll
        for (int j = 0; j < 4; j++)
            bf[j] = *reinterpret_cast<const f16x8*>(&Bs[(wn + j * 16 + lrow) * 32 + quad * 8]);
        #pragma unroll
        for (int i = 0; i < 4; i++)
            #pragma unroll
            for (int j = 0; j < 4; j++)
                acc[i][j] = __builtin_amdgcn_mfma_f32_16x16x32_f16(af[i], bf[j], acc[i][j], 0, 0, 0);
        __syncthreads();
    }

    #pragma unroll
    for (int j = 0; j < 4; j++) {
        int m = m0 + wn + j * 16 + lrow;
        float bb = bias[m];
        #pragma unroll
        for (int i = 0; i < 4; i++)
            #pragma unroll
            for (int r = 0; r < 4; r++) {
                int n = n0 + wm + i * 16 + quad * 4 + r;
                out[(size_t)n * D_ + m] = acc[i][j][r] + bb;
            }
    }
}

// ------------------------------------------------------------------- launcher
extern "C" void kernel_launch(void* const* d_in, const int* in_sizes, int n_in,
                              void* d_out, int out_size, void* d_ws, size_t ws_size,
                              hipStream_t stream) {
    (void)in_sizes; (void)n_in; (void)out_size; (void)ws_size;
    const float* x     = (const float*)d_in[0];
    const float* w_qkv = (const float*)d_in[1];
    const float* b_qkv = (const float*)d_in[2];
    const float* w_out = (const float*)d_in[3];
    const float* b_out = (const float*)d_in[4];
    float* out = (float*)d_out;

    char* ws = (char*)d_ws;
    const size_t MB = 1024 * 1024;
    f16* xb    = (f16*)(ws);             // 16 MB  (reused as ctx after GEMM1)
    f16* wqkvT = (f16*)(ws + 16 * MB);   // 6 MB
    f16* woutT = (f16*)(ws + 22 * MB);   // 2 MB
    f16* qs    = (f16*)(ws + 24 * MB);   // 16 MB  [b][h][s][d], pre-scaled
    f16* kk    = (f16*)(ws + 40 * MB);   // 16 MB  [b][h][s][d]
    f16* vTb   = (f16*)(ws + 72 * MB);   // 16 MB  [b][h][d][s] (written by gemm_qkv)
    f16* ctx   = xb;                     // alias: xb dead after gemm_qkv

    cvt_x_kernel<<<(N_ * D_) / (256 * 4), 256, 0, stream>>>(x, xb);
    wt_cvt_kernel<<<dim3(M3_ / 32, D_ / 32), 256, 0, stream>>>(w_qkv, wqkvT, D_, M3_);
    wt_cvt_kernel<<<dim3(D_ / 32, D_ / 32), 256, 0, stream>>>(w_out, woutT, D_, D_);
    gemm_qkv_kernel<<<dim3((N_ / 256) * (M3_ / 256)), 512, 0, stream>>>(xb, wqkvT, b_qkv, qs, kk, vTb);
    attn_kernel<<<(B_ * H_) * (S_ / 128), 256, 0, stream>>>(qs, kk, vTb, ctx);
    gemm_out_kernel<<<dim3(N_ / 128, D_ / 128), 256, 0, stream>>>(ctx, woutT, b_out, out);
}

// Round 6
// 271.213 us; speedup vs baseline: 1.0082x; 1.0037x over previous
//
#include <hip/hip_runtime.h>

#define D_ 1024
#define H_ 16
#define DH_ 64
#define S_ 2048
#define B_ 4
#define N_ (B_*S_)    // 8192 tokens
#define M3_ 3072
// SCALE * log2(e): fold into q so softmax uses exp2 directly
#define QSC_ 0.18033688011112042f

typedef _Float16 f16;
typedef _Float16 f16x8 __attribute__((ext_vector_type(8)));
typedef _Float16 f16x4 __attribute__((ext_vector_type(4)));
typedef _Float16 f16x2 __attribute__((ext_vector_type(2)));
typedef __fp16   h16x2 __attribute__((ext_vector_type(2)));
typedef float    f32x4 __attribute__((ext_vector_type(4)));

typedef __attribute__((address_space(1))) void gvoid;
typedef __attribute__((address_space(3))) void lvoid;

__device__ __forceinline__ void gl16(const f16* g, f16* l) {
    __builtin_amdgcn_global_load_lds((gvoid*)g, (lvoid*)l, 16, 0, 0);
}

__device__ __forceinline__ f16x2 pk_cvt(float a, float b) {
#if __has_builtin(__builtin_amdgcn_cvt_pkrtz)
    h16x2 t = __builtin_amdgcn_cvt_pkrtz(a, b);
    return __builtin_bit_cast(f16x2, t);
#else
    f16x2 r; r[0] = (f16)a; r[1] = (f16)b; return r;
#endif
}

// ---------------------------------------------------------------- cvt x -> fp16
__global__ __launch_bounds__(256) void cvt_x_kernel(const float* __restrict__ in,
                                                    f16* __restrict__ out) {
    size_t i = ((size_t)blockIdx.x * 256 + threadIdx.x) * 4;
    float4 f = *reinterpret_cast<const float4*>(in + i);
    f16x4 o;
    o[0] = (f16)f.x; o[1] = (f16)f.y; o[2] = (f16)f.z; o[3] = (f16)f.w;
    *reinterpret_cast<f16x4*>(out + i) = o;
}

// ------------------------------------------- weight transpose + convert to fp16
// in: [K][Nc] fp32  ->  out: [Nc][K] fp16
__global__ __launch_bounds__(256) void wt_cvt_kernel(const float* __restrict__ in,
                                                     f16* __restrict__ out,
                                                     int K, int Nc) {
    __shared__ float tile[32][33];
    int tx = threadIdx.x & 31, ty = threadIdx.x >> 5;
    int c = blockIdx.x * 32 + tx;
    #pragma unroll
    for (int i = 0; i < 4; i++) {
        int r = blockIdx.y * 32 + ty + i * 8;
        tile[ty + i * 8][tx] = in[(size_t)r * Nc + c];
    }
    __syncthreads();
    #pragma unroll
    for (int i = 0; i < 4; i++) {
        int r2 = blockIdx.x * 32 + ty + i * 8;   // out row (col of in)
        int c2 = blockIdx.y * 32 + tx;           // out col (row of in)
        out[(size_t)r2 * K + c2] = (f16)tile[tx][ty + i * 8];
    }
}

// --------------------------------------------------------------- QKV GEMM v3
// 256x256 tile, BK=64 in 2 k-chunks; 8 waves (2M x 4N), wave owns 128x64
// (acc[8][4]). Double-buffered k-chunk staging via global_load_lds, counted
// vmcnt(4) across raw s_barriers (ledger: at each phase's wait, the loads
// waited on were issued one full phase earlier; never drains to 0 mid-loop).
// v3 fixes vs v2 (PMC-driven):
//  - 4-bit bank swizzle x(r) = (r + (r>>2)) & 3: col p of row r stores part
//    p^x(r). Per 16-lane read phase all 8 bank-quads covered exactly 2x
//    (2-way = free, m136). v2's 2-bit XOR was 4-way (4.7M conflicts measured).
//  - XCD-compact block swizzle: XCD x owns n-panels [4x,4x+4) (2MB A slice,
//    stays L2-resident all kernel) x all 12 m-panels, n-fastest order so each
//    B panel is used by 4 temporally-adjacent blocks then retired.
//    v2 gave each XCD ALL of A (16MB >> 4MB L2) -> 103MB HBM fetch.
__global__ __launch_bounds__(512, 2) void gemm_qkv_kernel(
        const f16* __restrict__ A, const f16* __restrict__ Bt,
        const float* __restrict__ bias,
        f16* __restrict__ qo, f16* __restrict__ ko, f16* __restrict__ vTo) {
    __shared__ __align__(16) f16 S[2 * 4 * 8192];   // 128 KiB
    const int tid  = threadIdx.x;
    const int lane = tid & 63, w = tid >> 6;
    const int quad = lane >> 4, lrow = lane & 15;
    const int G  = w >> 2;             // M-half (0/1)
    const int wn = (w & 3) * 64;       // N-quarter

    // XCD swizzle: xcd = id&7 (round-robin dispatch); 48 blocks per XCD =
    // 4 n-panels (n-fastest) x 12 m-panels.
    const int id   = blockIdx.x;
    const int xcd  = id & 7, idx = id >> 3;
    const int n0 = (xcd * 4 + (idx & 3)) * 256;
    const int m0 = (idx >> 2) * 256;

    f32x4 acc[8][4];
    #pragma unroll
    for (int i = 0; i < 8; i++)
        #pragma unroll
        for (int j = 0; j < 4; j++) acc[i][j] = {0.f, 0.f, 0.f, 0.f};

    // staging: chunk c -> LDS 16B slot c of a region; row r=c>>2, col p=c&3.
    // col p stores original part p ^ x(r), x(r) = (r + (r>>2)) & 3.
    const int c0 = tid, c1 = tid + 512;
    const int r0 = c0 >> 2, r1 = c1 >> 2;
    const int x0 = (r0 + (r0 >> 2)) & 3, x1 = (r1 + (r1 >> 2)) & 3;
    const int g0 = r0 * D_ + (((c0 & 3) ^ x0) * 8);
    const int g1 = r1 * D_ + (((c1 & 3) ^ x1) * 8);
    const f16* Ab = A  + (size_t)n0 * D_;
    const f16* Bb = Bt + (size_t)m0 * D_;

    // frag reads: part quad of row r sits at col quad^x(r); frag-row bases are
    // multiples of 16 so x(row) == x(lrow) -> constant per-lane offset.
    const int xq8   = (quad ^ ((lrow + (lrow >> 2)) & 3)) * 8;
    const int abase = (G * 128 + lrow) * 32 + xq8;   // + i*512
    const int bbase = (wn + lrow) * 32 + xq8;        // + j*512

#define STAGE_QKV(ktn, ck, nb) do {                                          \
    const int ko_ = (ktn) * 64 + (ck) * 32;                                  \
    gl16(Ab + ko_ + g0, &S[(((nb) * 4 + (ck)) * 8192) + c0 * 8]);            \
    gl16(Ab + ko_ + g1, &S[(((nb) * 4 + (ck)) * 8192) + c1 * 8]);            \
    gl16(Bb + ko_ + g0, &S[(((nb) * 4 + 2 + (ck)) * 8192) + c0 * 8]);        \
    gl16(Bb + ko_ + g1, &S[(((nb) * 4 + 2 + (ck)) * 8192) + c1 * 8]);        \
} while (0)

    // prologue: stage tile 0 chunk0 + chunk1 (8 loads); wait chunk0 only.
    STAGE_QKV(0, 0, 0);
    STAGE_QKV(0, 1, 0);
    asm volatile("s_waitcnt vmcnt(4)" ::: "memory");
    __builtin_amdgcn_s_barrier();
    __builtin_amdgcn_sched_barrier(0);

    #pragma unroll 1
    for (int kt = 0; kt < 15; kt++) {
        const int buf = kt & 1, nb = buf ^ 1;
        #pragma unroll
        for (int ck = 0; ck < 2; ck++) {
            const f16* Sa = &S[(buf * 4 + ck) * 8192];
            const f16* Sb = &S[(buf * 4 + 2 + ck) * 8192];
            f16x8 af[8], bf[4];
            #pragma unroll
            for (int i = 0; i < 8; i++)
                af[i] = *reinterpret_cast<const f16x8*>(Sa + abase + i * 512);
            #pragma unroll
            for (int j = 0; j < 4; j++)
                bf[j] = *reinterpret_cast<const f16x8*>(Sb + bbase + j * 512);
            STAGE_QKV(kt + 1, ck, nb);
            __builtin_amdgcn_sched_barrier(0);
            __builtin_amdgcn_s_setprio(1);
            #pragma unroll
            for (int i = 0; i < 8; i++)
                #pragma unroll
                for (int j = 0; j < 4; j++)
                    acc[i][j] = __builtin_amdgcn_mfma_f32_16x16x32_f16(af[i], bf[j], acc[i][j], 0, 0, 0);
            __builtin_amdgcn_s_setprio(0);
            // 8 outstanding (prev phase's 4 + this phase's 4): wait the old 4.
            asm volatile("s_waitcnt vmcnt(4)" ::: "memory");
            __builtin_amdgcn_s_barrier();
            __builtin_amdgcn_sched_barrier(0);
        }
    }
    // peeled tail kt = 15 (buf = 1): no staging; drain once between phases.
    {
        const int buf = 1;
        #pragma unroll
        for (int ck = 0; ck < 2; ck++) {
            const f16* Sa = &S[(buf * 4 + ck) * 8192];
            const f16* Sb = &S[(buf * 4 + 2 + ck) * 8192];
            f16x8 af[8], bf[4];
            #pragma unroll
            for (int i = 0; i < 8; i++)
                af[i] = *reinterpret_cast<const f16x8*>(Sa + abase + i * 512);
            #pragma unroll
            for (int j = 0; j < 4; j++)
                bf[j] = *reinterpret_cast<const f16x8*>(Sb + bbase + j * 512);
            __builtin_amdgcn_s_setprio(1);
            #pragma unroll
            for (int i = 0; i < 8; i++)
                #pragma unroll
                for (int j = 0; j < 4; j++)
                    acc[i][j] = __builtin_amdgcn_mfma_f32_16x16x32_f16(af[i], bf[j], acc[i][j], 0, 0, 0);
            __builtin_amdgcn_s_setprio(0);
            if (ck == 0) {
                asm volatile("s_waitcnt vmcnt(0)" ::: "memory");
                __builtin_amdgcn_s_barrier();
                __builtin_amdgcn_sched_barrier(0);
            }
        }
    }
#undef STAGE_QKV

    // epilogue: bias + route. q/k: [b][h][s][d]; v: [b][h][d][s] packed x4
    #pragma unroll
    for (int j = 0; j < 4; j++) {
        int m   = m0 + wn + j * 16 + lrow;
        int sec = m >> 10;
        int hd  = m & 1023;
        int hh  = hd >> 6, d = hd & 63;
        float bb = bias[m];
        if (sec == 2) {
            #pragma unroll
            for (int i = 0; i < 8; i++) {
                int n = n0 + G * 128 + i * 16 + quad * 4;   // r=0 element
                int bidx = n >> 11, s = n & 2047;
                f16x4 o;
                #pragma unroll
                for (int r = 0; r < 4; r++) o[r] = (f16)(acc[i][j][r] + bb);
                *reinterpret_cast<f16x4*>(
                    &vTo[(((size_t)(bidx * H_ + hh)) * DH_ + d) * S_ + s]) = o;
            }
        } else {
            f16* dst = (sec == 0) ? qo : ko;
            float sc = (sec == 0) ? QSC_ : 1.0f;
            #pragma unroll
            for (int i = 0; i < 8; i++) {
                #pragma unroll
                for (int r = 0; r < 4; r++) {
                    int n = n0 + G * 128 + i * 16 + quad * 4 + r;
                    int bidx = n >> 11, s = n & 2047;
                    dst[(((size_t)(bidx * H_ + hh)) * S_ + s) * DH_ + d] =
                        (f16)((acc[i][j][r] + bb) * sc);
                }
            }
        }
    }
}

// --------------------------------------------------------------- flash attention
// v5 (R3, 76.4us): 128 q rows/block, 64-KV tiles double-buffered via
// global_load_lds with source-side XOR swizzles (0 bank conflicts), 4 blocks/CU,
// intra-tile software pipeline + s_setprio.
// q,k: [bh][s][64] (q pre-scaled by QSC_); vT: [bh][64][s]; ctx: [b*S][1024] f16
__global__ __launch_bounds__(256, 4) void attn_kernel(
        const f16* __restrict__ q, const f16* __restrict__ k,
        const f16* __restrict__ vT, f16* __restrict__ ctx) {
    __shared__ __align__(16) f16 Ks[2][64 * 64];   // [slot][d], swizzled parts
    __shared__ __align__(16) f16 Vs[2][64 * 64];   // [d][kv],  swizzled parts
    const int tid  = threadIdx.x;
    const int lane = tid & 63, w = tid >> 6;
    const int quad = lane >> 4, lrow = lane & 15;
    const int id = blockIdx.x;
    const int bh = id & 63;                  // id%8 == bh%8 -> same XCD per head
    const int q0 = (id >> 6) * 128;          // 128 q rows per block, 32 per wave
    const int b  = bh >> 4, h = bh & 15;
    const f16* qb = q  + (size_t)bh * S_ * DH_;
    const f16* kb = k  + (size_t)bh * S_ * DH_;
    const f16* vb = vT + (size_t)bh * DH_ * S_;

    // Q fragments (B-operand: n=lane&15 -> q, k=quad*8+j -> d); 2 frags/wave
    f16x8 qf[2][2];
    #pragma unroll
    for (int f = 0; f < 2; f++)
        #pragma unroll
        for (int hf = 0; hf < 2; hf++)
            qf[f][hf] = *reinterpret_cast<const f16x8*>(
                qb + (size_t)(q0 + w * 32 + f * 16 + lrow) * DH_ + hf * 32 + quad * 8);

    // ones fragment for l-accumulation MFMA (A[m][k] = 1)
    f16x8 ones8;
    #pragma unroll
    for (int i = 0; i < 8; i++) ones8[i] = (f16)1.f;

    f32x4 lacc[2];    // all 16 C-rows hold the same full kv-sum per q-col
    f32x4 ot[2][4];   // O^T accum: col=lane&15 -> q, row=dj*16+quad*4+r -> d
    #pragma unroll
    for (int f = 0; f < 2; f++) {
        lacc[f] = {0.f, 0.f, 0.f, 0.f};
        #pragma unroll
        for (int dj = 0; dj < 4; dj++) ot[f][dj] = {0.f, 0.f, 0.f, 0.f};
    }

    // K gl16 source offsets: chunk c -> LDS slot s=c>>3, 16B part p=c&7.
    // Stored data = K[ sigma^{-1}(s) ][ (p ^ (s&7))*8 .. +8 ).
    // sigma^{-1}: s -> (s&~31) | (((s>>2)&3)<<3) | (((s>>4)&1)<<2) | (s&3)
    // V gl16 source offsets: chunk c -> LDS row d=c>>3, part p=c&7 stores
    // kv-part p^(d&7) of global row d.
    int koff[2], voff[2];
    #pragma unroll
    for (int i = 0; i < 2; i++) {
        int c = i * 256 + tid;
        int s = c >> 3, p = c & 7;
        int g = (s & ~31) | (((s >> 2) & 3) << 3) | (((s >> 4) & 1) << 2) | (s & 3);
        koff[i] = g * DH_ + ((p ^ (s & 7)) * 8);
        voff[i] = s * S_ + ((p ^ (s & 7)) * 8);   // for V: s is the d-row
    }

    // stage tile 0 into buf 0
    #pragma unroll
    for (int i = 0; i < 2; i++) {
        gl16(kb + koff[i], &Ks[0][(i * 256 + tid) * 8]);
        gl16(vb + voff[i], &Vs[0][(i * 256 + tid) * 8]);
    }
    __syncthreads();

    // read-side XOR chunk offsets (elements) for K
    const int xr0 = (quad ^ (lrow & 7)) * 8;          // d-part quad
    const int xr1 = ((quad + 4) ^ (lrow & 7)) * 8;    // d-part quad+4

    union PU { f16x8 v; f16x2 w[4]; };

    const int NT = S_ / 64;
    for (int kt = 0; kt < NT; kt++) {
        const int cur = kt & 1;
        const f16* Kc = Ks[cur];
        const f16* Vc = Vs[cur];

        // ---- QK strips 0,1 (t=0)
        f32x4 st0[2][2];
        __builtin_amdgcn_s_setprio(1);
        #pragma unroll
        for (int half = 0; half < 2; half++) {
            const int rb = (half * 16 + lrow) * 64;
            const f16x8 k0 = *reinterpret_cast<const f16x8*>(&Kc[rb + xr0]);
            const f16x8 k1 = *reinterpret_cast<const f16x8*>(&Kc[rb + xr1]);
            #pragma unroll
            for (int f = 0; f < 2; f++) {
                f32x4 s = {0.f, 0.f, 0.f, 0.f};
                s = __builtin_amdgcn_mfma_f32_16x16x32_f16(k0, qf[f][0], s, 0, 0, 0);
                s = __builtin_amdgcn_mfma_f32_16x16x32_f16(k1, qf[f][1], s, 0, 0, 0);
                st0[half][f] = s;
            }
        }
        __builtin_amdgcn_s_setprio(0);

        // ---- issue next tile staging (lands during this tile's compute)
        if (kt + 1 < NT) {
            const size_t kv1 = (size_t)(kt + 1) * 64;
            #pragma unroll
            for (int i = 0; i < 2; i++) {
                gl16(kb + kv1 * DH_ + koff[i], &Ks[cur ^ 1][(i * 256 + tid) * 8]);
                gl16(vb + kv1 + voff[i],       &Vs[cur ^ 1][(i * 256 + tid) * 8]);
            }
        }

        // ---- exp + pack t=0
        PU p0[2];
        #pragma unroll
        for (int half = 0; half < 2; half++)
            #pragma unroll
            for (int f = 0; f < 2; f++) {
                f16x2 lo = pk_cvt(__builtin_amdgcn_exp2f(st0[half][f][0]),
                                  __builtin_amdgcn_exp2f(st0[half][f][1]));
                f16x2 hi = pk_cvt(__builtin_amdgcn_exp2f(st0[half][f][2]),
                                  __builtin_amdgcn_exp2f(st0[half][f][3]));
                p0[f].w[half * 2 + 0] = lo;
                p0[f].w[half * 2 + 1] = hi;
            }

        // ---- QK strips 2,3 (t=1) — bridges exp(t0)->PV(t0) dependency gap
        f32x4 st1[2][2];
        __builtin_amdgcn_s_setprio(1);
        #pragma unroll
        for (int half = 0; half < 2; half++) {
            const int rb = ((2 + half) * 16 + lrow) * 64;
            const f16x8 k0 = *reinterpret_cast<const f16x8*>(&Kc[rb + xr0]);
            const f16x8 k1 = *reinterpret_cast<const f16x8*>(&Kc[rb + xr1]);
            #pragma unroll
            for (int f = 0; f < 2; f++) {
                f32x4 s = {0.f, 0.f, 0.f, 0.f};
                s = __builtin_amdgcn_mfma_f32_16x16x32_f16(k0, qf[f][0], s, 0, 0, 0);
                s = __builtin_amdgcn_mfma_f32_16x16x32_f16(k1, qf[f][1], s, 0, 0, 0);
                st1[half][f] = s;
            }
        }
        __builtin_amdgcn_s_setprio(0);

        // ---- V fragments t=0
        f16x8 vf0[4];
        #pragma unroll
        for (int dj = 0; dj < 4; dj++)
            vf0[dj] = *reinterpret_cast<const f16x8*>(
                &Vc[(dj * 16 + lrow) * 64 + ((quad ^ (lrow & 7)) * 8)]);

        // ---- PV t=0 + lacc0
        __builtin_amdgcn_s_setprio(1);
        #pragma unroll
        for (int dj = 0; dj < 4; dj++)
            #pragma unroll
            for (int f = 0; f < 2; f++)
                ot[f][dj] = __builtin_amdgcn_mfma_f32_16x16x32_f16(vf0[dj], p0[f].v, ot[f][dj], 0, 0, 0);
        #pragma unroll
        for (int f = 0; f < 2; f++)
            lacc[f] = __builtin_amdgcn_mfma_f32_16x16x32_f16(ones8, p0[f].v, lacc[f], 0, 0, 0);
        __builtin_amdgcn_s_setprio(0);

        // ---- exp + pack t=1
        PU p1[2];
        #pragma unroll
        for (int half = 0; half < 2; half++)
            #pragma unroll
            for (int f = 0; f < 2; f++) {
                f16x2 lo = pk_cvt(__builtin_amdgcn_exp2f(st1[half][f][0]),
                                  __builtin_amdgcn_exp2f(st1[half][f][1]));
                f16x2 hi = pk_cvt(__builtin_amdgcn_exp2f(st1[half][f][2]),
                                  __builtin_amdgcn_exp2f(st1[half][f][3]));
                p1[f].w[half * 2 + 0] = lo;
                p1[f].w[half * 2 + 1] = hi;
            }

        // ---- V fragments t=1
        f16x8 vf1[4];
        #pragma unroll
        for (int dj = 0; dj < 4; dj++)
            vf1[dj] = *reinterpret_cast<const f16x8*>(
                &Vc[(dj * 16 + lrow) * 64 + (((4 + quad) ^ (lrow & 7)) * 8)]);

        // ---- PV t=1 + lacc1
        __builtin_amdgcn_s_setprio(1);
        #pragma unroll
        for (int dj = 0; dj < 4; dj++)
            #pragma unroll
            for (int f = 0; f < 2; f++)
                ot[f][dj] = __builtin_amdgcn_mfma_f32_16x16x32_f16(vf1[dj], p1[f].v, ot[f][dj], 0, 0, 0);
        #pragma unroll
        for (int f = 0; f < 2; f++)
            lacc[f] = __builtin_amdgcn_mfma_f32_16x16x32_f16(ones8, p1[f].v, lacc[f], 0, 0, 0);
        __builtin_amdgcn_s_setprio(0);

        __syncthreads();   // drains gl16 (vmcnt) -> next buffer ready
    }

    #pragma unroll
    for (int f = 0; f < 2; f++) {
        float inv = 1.0f / lacc[f][0];
        int qrow = q0 + w * 32 + f * 16 + lrow;
        #pragma unroll
        for (int dj = 0; dj < 4; dj++) {
            f16x4 o;
            #pragma unroll
            for (int r = 0; r < 4; r++) o[r] = (f16)(ot[f][dj][r] * inv);
            *reinterpret_cast<f16x4*>(
                &ctx[((size_t)(b * S_ + qrow)) * D_ + h * DH_ + dj * 16 + quad * 4]) = o;
        }
    }
}

// --------------------------------------------------------------- output GEMM
// out[n][m] = sum_k ctx[n][k]*Bt[m][k] + bias[m]   (fp32 out)
__global__ __launch_bounds__(256) void gemm_out_kernel(
        const f16* __restrict__ A, const f16* __restrict__ Bt,
        const float* __restrict__ bias, float* __restrict__ out) {
    __shared__ __align__(16) f16 As[128 * 32];
    __shared__ __align__(16) f16 Bs[128 * 32];
    const int tid  = threadIdx.x;
    const int lane = tid & 63, w = tid >> 6;
    const int quad = lane >> 4, lrow = lane & 15;
    const int wm = (w & 1) * 64, wn = (w >> 1) * 64;
    const int n0 = blockIdx.x * 128, m0 = blockIdx.y * 128;

    f32x4 acc[4][4];
    #pragma unroll
    for (int i = 0; i < 4; i++)
        #pragma unroll
        for (int j = 0; j < 4; j++) acc[i][j] = {0.f, 0.f, 0.f, 0.f};

    const int ar0 = tid >> 2, ap0 = tid & 3;
    const f16* Ag0 = A  + (size_t)(n0 + ar0) * D_ + ap0 * 8;
    const f16* Ag1 = Ag0 + (size_t)64 * D_;
    const f16* Bg0 = Bt + (size_t)(m0 + ar0) * D_ + ap0 * 8;
    const f16* Bg1 = Bg0 + (size_t)64 * D_;
    f16* Asl = As + tid * 8;
    f16* Bsl = Bs + tid * 8;

    for (int kt = 0; kt < D_ / 32; kt++) {
        gl16(Ag0 + kt * 32, Asl);
        gl16(Ag1 + kt * 32, Asl + 64 * 32);
        gl16(Bg0 + kt * 32, Bsl);
        gl16(Bg1 + kt * 32, Bsl + 64 * 32);
        __syncthreads();
        f16x8 af[4], bf[4];
        #pragma unroll
        for (int i = 0; i < 4; i++)
            af[i] = *reinterpret_cast<const f16x8*>(&As[(wm + i * 16 + lrow) * 32 + quad * 8]);
        #pragma unroll
        for (int j = 0; j < 4; j++)
            bf[j] = *reinterpret_cast<const f16x8*>(&Bs[(wn + j * 16 + lrow) * 32 + quad * 8]);
        #pragma unroll
        for (int i = 0; i < 4; i++)
            #pragma unroll
            for (int j = 0; j < 4; j++)
                acc[i][j] = __builtin_amdgcn_mfma_f32_16x16x32_f16(af[i], bf[j], acc[i][j], 0, 0, 0);
        __syncthreads();
    }

    #pragma unroll
    for (int j = 0; j < 4; j++) {
        int m = m0 + wn + j * 16 + lrow;
        float bb = bias[m];
        #pragma unroll
        for (int i = 0; i < 4; i++)
            #pragma unroll
            for (int r = 0; r < 4; r++) {
                int n = n0 + wm + i * 16 + quad * 4 + r;
                out[(size_t)n * D_ + m] = acc[i][j][r] + bb;
            }
    }
}

// ------------------------------------------------------------------- launcher
extern "C" void kernel_launch(void* const* d_in, const int* in_sizes, int n_in,
                              void* d_out, int out_size, void* d_ws, size_t ws_size,
                              hipStream_t stream) {
    (void)in_sizes; (void)n_in; (void)out_size; (void)ws_size;
    const float* x     = (const float*)d_in[0];
    const float* w_qkv = (const float*)d_in[1];
    const float* b_qkv = (const float*)d_in[2];
    const float* w_out = (const float*)d_in[3];
    const float* b_out = (const float*)d_in[4];
    float* out = (float*)d_out;

    char* ws = (char*)d_ws;
    const size_t MB = 1024 * 1024;
    f16* xb    = (f16*)(ws);             // 16 MB  (reused as ctx after GEMM1)
    f16* wqkvT = (f16*)(ws + 16 * MB);   // 6 MB
    f16* woutT = (f16*)(ws + 22 * MB);   // 2 MB
    f16* qs    = (f16*)(ws + 24 * MB);   // 16 MB  [b][h][s][d], pre-scaled
    f16* kk    = (f16*)(ws + 40 * MB);   // 16 MB  [b][h][s][d]
    f16* vTb   = (f16*)(ws + 72 * MB);   // 16 MB  [b][h][d][s] (written by gemm_qkv)
    f16* ctx   = xb;                     // alias: xb dead after gemm_qkv

    cvt_x_kernel<<<(N_ * D_) / (256 * 4), 256, 0, stream>>>(x, xb);
    wt_cvt_kernel<<<dim3(M3_ / 32, D_ / 32), 256, 0, stream>>>(w_qkv, wqkvT, D_, M3_);
    wt_cvt_kernel<<<dim3(D_ / 32, D_ / 32), 256, 0, stream>>>(w_out, woutT, D_, D_);
    gemm_qkv_kernel<<<dim3((N_ / 256) * (M3_ / 256)), 512, 0, stream>>>(xb, wqkvT, b_qkv, qs, kk, vTb);
    attn_kernel<<<(B_ * H_) * (S_ / 128), 256, 0, stream>>>(qs, kk, vTb, ctx);
    gemm_out_kernel<<<dim3(N_ / 128, D_ / 128), 256, 0, stream>>>(ctx, woutT, b_out, out);
}

// Round 7
// 268.786 us; speedup vs baseline: 1.0173x; 1.0090x over previous
//
#include <hip/hip_runtime.h>

#define D_ 1024
#define H_ 16
#define DH_ 64
#define S_ 2048
#define B_ 4
#define N_ (B_*S_)    // 8192 tokens
#define M3_ 3072
// SCALE * log2(e): fold into q so softmax uses exp2 directly
#define QSC_ 0.18033688011112042f

typedef _Float16 f16;
typedef _Float16 f16x8 __attribute__((ext_vector_type(8)));
typedef _Float16 f16x4 __attribute__((ext_vector_type(4)));
typedef _Float16 f16x2 __attribute__((ext_vector_type(2)));
typedef __fp16   h16x2 __attribute__((ext_vector_type(2)));
typedef float    f32x4 __attribute__((ext_vector_type(4)));

typedef __attribute__((address_space(1))) void gvoid;
typedef __attribute__((address_space(3))) void lvoid;

__device__ __forceinline__ void gl16(const f16* g, f16* l) {
    __builtin_amdgcn_global_load_lds((gvoid*)g, (lvoid*)l, 16, 0, 0);
}

__device__ __forceinline__ f16x2 pk_cvt(float a, float b) {
#if __has_builtin(__builtin_amdgcn_cvt_pkrtz)
    h16x2 t = __builtin_amdgcn_cvt_pkrtz(a, b);
    return __builtin_bit_cast(f16x2, t);
#else
    f16x2 r; r[0] = (f16)a; r[1] = (f16)b; return r;
#endif
}

// ---------------------------------------------------------------- cvt x -> fp16
__global__ __launch_bounds__(256) void cvt_x_kernel(const float* __restrict__ in,
                                                    f16* __restrict__ out) {
    size_t i = ((size_t)blockIdx.x * 256 + threadIdx.x) * 4;
    float4 f = *reinterpret_cast<const float4*>(in + i);
    f16x4 o;
    o[0] = (f16)f.x; o[1] = (f16)f.y; o[2] = (f16)f.z; o[3] = (f16)f.w;
    *reinterpret_cast<f16x4*>(out + i) = o;
}

// ------------------------------------------- weight transpose + convert to fp16
// in: [K][Nc] fp32  ->  out: [Nc][K] fp16
__global__ __launch_bounds__(256) void wt_cvt_kernel(const float* __restrict__ in,
                                                     f16* __restrict__ out,
                                                     int K, int Nc) {
    __shared__ float tile[32][33];
    int tx = threadIdx.x & 31, ty = threadIdx.x >> 5;
    int c = blockIdx.x * 32 + tx;
    #pragma unroll
    for (int i = 0; i < 4; i++) {
        int r = blockIdx.y * 32 + ty + i * 8;
        tile[ty + i * 8][tx] = in[(size_t)r * Nc + c];
    }
    __syncthreads();
    #pragma unroll
    for (int i = 0; i < 4; i++) {
        int r2 = blockIdx.x * 32 + ty + i * 8;   // out row (col of in)
        int c2 = blockIdx.y * 32 + tx;           // out col (row of in)
        out[(size_t)r2 * K + c2] = (f16)tile[tx][ty + i * 8];
    }
}

// --------------------------------------------------------------- QKV GEMM v4
// 256x256 tile, BK=64, 8 waves (2M x 4N), wave owns 128x64 (acc[8][4]).
// v4: FINE 4-PHASE schedule per K-tile (m196/m201: the fine interleave is the
// lever; v3's coarse 2-phase left MfmaUtil at the 26% floor).
// Phases (ck,ih): p1(ck0,ih0) p2(ck0,ih1) p3(ck1,ih0) p4(ck1,ih1); each phase
// {6-8 ds_read_b128 ; 2 gl16 of ONE quarter of tile kt+1 ; [counted vmcnt] ;
//  s_barrier ; 16 MFMA (setprio)}.
// Issue/wait ledger (steady state, outstanding after each step):
//   entry p1: [B1(kt),A1(kt)]=4        p1 issues B0(kt+1) -> 6
//   p2 issues A0(kt+1) -> 8; vmcnt(4) retires B1,A1(kt) (validates p3/p4)
//   p3 issues B1(kt+1) -> 6
//   p4 issues A1(kt+1) -> 8; vmcnt(4) retires B0,A0(kt+1) (validates kt+1 p1)
// Every waited load was issued 2-4 phases earlier; never drains to 0 mid-loop.
// Overwrite safety: each gl16 write lands >=3 barriers after that region's
// last read (all writes target buf^1; all reads target buf).
// LDS 128 KiB = [2 buf][4 rgn: A-ck0,A-ck1,B-ck0,B-ck1][8192 f16], 4-bit bank
// swizzle x(r)=(r+(r>>2))&3 (R6: conflicts = benign 2/read aliasing, ~free).
__global__ __launch_bounds__(512, 2) void gemm_qkv_kernel(
        const f16* __restrict__ A, const f16* __restrict__ Bt,
        const float* __restrict__ bias,
        f16* __restrict__ qo, f16* __restrict__ ko, f16* __restrict__ vTo) {
    __shared__ __align__(16) f16 S[2 * 4 * 8192];   // 128 KiB
    const int tid  = threadIdx.x;
    const int lane = tid & 63, w = tid >> 6;
    const int quad = lane >> 4, lrow = lane & 15;
    const int G  = w >> 2;             // M-half (0/1)
    const int wn = (w & 3) * 64;       // N-quarter

    // XCD-compact swizzle (R6-verified: FETCH 103->41MB): xcd owns 4 n-panels
    // (2MB A slice, L2-resident) x 12 m-panels, n-fastest.
    const int id   = blockIdx.x;
    const int xcd  = id & 7, idx = id >> 3;
    const int n0 = (xcd * 4 + (idx & 3)) * 256;
    const int m0 = (idx >> 2) * 256;

    f32x4 acc[8][4];
    #pragma unroll
    for (int i = 0; i < 8; i++)
        #pragma unroll
        for (int j = 0; j < 4; j++) acc[i][j] = {0.f, 0.f, 0.f, 0.f};

    // staging: region slot c (16B): row r=c>>2, col p=c&3; col p stores part
    // p^x(r), x(r)=(r+(r>>2))&3.
    const int c0 = tid, c1 = tid + 512;
    const int r0 = c0 >> 2, r1 = c1 >> 2;
    const int x0 = (r0 + (r0 >> 2)) & 3, x1 = (r1 + (r1 >> 2)) & 3;
    const int g0 = r0 * D_ + (((c0 & 3) ^ x0) * 8);
    const int g1 = r1 * D_ + (((c1 & 3) ^ x1) * 8);
    const f16* Ab = A  + (size_t)n0 * D_;
    const f16* Bb = Bt + (size_t)m0 * D_;

    // frag reads: part quad of row r at col quad^x(r); frag-row bases are
    // multiples of 16 so x(row)==x(lrow).
    const int xq8   = (quad ^ ((lrow + (lrow >> 2)) & 3)) * 8;
    const int abase = (G * 128 + lrow) * 32 + xq8;   // + i*512
    const int bbase = (wn + lrow) * 32 + xq8;        // + j*512

#define STG_A(ktn, ck, nb) do {                                              \
    const int ko_ = (ktn) * 64 + (ck) * 32;                                  \
    gl16(Ab + ko_ + g0, &S[(((nb) * 4 + (ck)) * 8192) + c0 * 8]);            \
    gl16(Ab + ko_ + g1, &S[(((nb) * 4 + (ck)) * 8192) + c1 * 8]);            \
} while (0)
#define STG_B(ktn, ck, nb) do {                                              \
    const int ko_ = (ktn) * 64 + (ck) * 32;                                  \
    gl16(Bb + ko_ + g0, &S[(((nb) * 4 + 2 + (ck)) * 8192) + c0 * 8]);        \
    gl16(Bb + ko_ + g1, &S[(((nb) * 4 + 2 + (ck)) * 8192) + c1 * 8]);        \
} while (0)
#define SYNC_PT() do {                                                       \
    __builtin_amdgcn_sched_barrier(0);                                       \
    __builtin_amdgcn_s_barrier();                                            \
    __builtin_amdgcn_sched_barrier(0);                                       \
} while (0)

    // prologue: B0(0),A0(0),B1(0),A1(0); wait first 4 -> invariant established
    STG_B(0, 0, 0); STG_A(0, 0, 0); STG_B(0, 1, 0); STG_A(0, 1, 0);
    asm volatile("s_waitcnt vmcnt(4)" ::: "memory");
    SYNC_PT();

    #pragma unroll 1
    for (int kt = 0; kt < 15; kt++) {
        const int buf = kt & 1, nb = buf ^ 1;
        const f16* Sa0 = &S[(buf * 4 + 0) * 8192];
        const f16* Sa1 = &S[(buf * 4 + 1) * 8192];
        const f16* Sb0 = &S[(buf * 4 + 2) * 8192];
        const f16* Sb1 = &S[(buf * 4 + 3) * 8192];
        f16x8 af[4], bf[4];

        // ---- p1 (ck0, ih0)
        #pragma unroll
        for (int i = 0; i < 4; i++)
            af[i] = *reinterpret_cast<const f16x8*>(Sa0 + abase + i * 512);
        #pragma unroll
        for (int j = 0; j < 4; j++)
            bf[j] = *reinterpret_cast<const f16x8*>(Sb0 + bbase + j * 512);
        STG_B(kt + 1, 0, nb);
        SYNC_PT();
        __builtin_amdgcn_s_setprio(1);
        #pragma unroll
        for (int i = 0; i < 4; i++)
            #pragma unroll
            for (int j = 0; j < 4; j++)
                acc[i][j] = __builtin_amdgcn_mfma_f32_16x16x32_f16(af[i], bf[j], acc[i][j], 0, 0, 0);
        __builtin_amdgcn_s_setprio(0);

        // ---- p2 (ck0, ih1)
        #pragma unroll
        for (int i = 0; i < 4; i++)
            af[i] = *reinterpret_cast<const f16x8*>(Sa0 + abase + (4 + i) * 512);
        STG_A(kt + 1, 0, nb);
        asm volatile("s_waitcnt vmcnt(4)" ::: "memory");   // retires ck1(kt)
        SYNC_PT();
        __builtin_amdgcn_s_setprio(1);
        #pragma unroll
        for (int i = 0; i < 4; i++)
            #pragma unroll
            for (int j = 0; j < 4; j++)
                acc[4 + i][j] = __builtin_amdgcn_mfma_f32_16x16x32_f16(af[i], bf[j], acc[4 + i][j], 0, 0, 0);
        __builtin_amdgcn_s_setprio(0);

        // ---- p3 (ck1, ih0)
        #pragma unroll
        for (int i = 0; i < 4; i++)
            af[i] = *reinterpret_cast<const f16x8*>(Sa1 + abase + i * 512);
        #pragma unroll
        for (int j = 0; j < 4; j++)
            bf[j] = *reinterpret_cast<const f16x8*>(Sb1 + bbase + j * 512);
        STG_B(kt + 1, 1, nb);
        SYNC_PT();
        __builtin_amdgcn_s_setprio(1);
        #pragma unroll
        for (int i = 0; i < 4; i++)
            #pragma unroll
            for (int j = 0; j < 4; j++)
                acc[i][j] = __builtin_amdgcn_mfma_f32_16x16x32_f16(af[i], bf[j], acc[i][j], 0, 0, 0);
        __builtin_amdgcn_s_setprio(0);

        // ---- p4 (ck1, ih1)
        #pragma unroll
        for (int i = 0; i < 4; i++)
            af[i] = *reinterpret_cast<const f16x8*>(Sa1 + abase + (4 + i) * 512);
        STG_A(kt + 1, 1, nb);
        asm volatile("s_waitcnt vmcnt(4)" ::: "memory");   // retires ck0(kt+1)
        SYNC_PT();
        __builtin_amdgcn_s_setprio(1);
        #pragma unroll
        for (int i = 0; i < 4; i++)
            #pragma unroll
            for (int j = 0; j < 4; j++)
                acc[4 + i][j] = __builtin_amdgcn_mfma_f32_16x16x32_f16(af[i], bf[j], acc[4 + i][j], 0, 0, 0);
        __builtin_amdgcn_s_setprio(0);
    }
    // ---- peeled tail kt=15 (buf=1): no staging; p2 wait drains to 0.
    {
        const f16* Sa0 = &S[(1 * 4 + 0) * 8192];
        const f16* Sa1 = &S[(1 * 4 + 1) * 8192];
        const f16* Sb0 = &S[(1 * 4 + 2) * 8192];
        const f16* Sb1 = &S[(1 * 4 + 3) * 8192];
        f16x8 af[4], bf[4];
        // p1
        #pragma unroll
        for (int i = 0; i < 4; i++)
            af[i] = *reinterpret_cast<const f16x8*>(Sa0 + abase + i * 512);
        #pragma unroll
        for (int j = 0; j < 4; j++)
            bf[j] = *reinterpret_cast<const f16x8*>(Sb0 + bbase + j * 512);
        #pragma unroll
        for (int i = 0; i < 4; i++)
            #pragma unroll
            for (int j = 0; j < 4; j++)
                acc[i][j] = __builtin_amdgcn_mfma_f32_16x16x32_f16(af[i], bf[j], acc[i][j], 0, 0, 0);
        // p2
        #pragma unroll
        for (int i = 0; i < 4; i++)
            af[i] = *reinterpret_cast<const f16x8*>(Sa0 + abase + (4 + i) * 512);
        #pragma unroll
        for (int i = 0; i < 4; i++)
            #pragma unroll
            for (int j = 0; j < 4; j++)
                acc[4 + i][j] = __builtin_amdgcn_mfma_f32_16x16x32_f16(af[i], bf[j], acc[4 + i][j], 0, 0, 0);
        asm volatile("s_waitcnt vmcnt(0)" ::: "memory");   // ck1(15) landed
        SYNC_PT();
        // p3 + p4
        #pragma unroll
        for (int i = 0; i < 4; i++)
            af[i] = *reinterpret_cast<const f16x8*>(Sa1 + abase + i * 512);
        #pragma unroll
        for (int j = 0; j < 4; j++)
            bf[j] = *reinterpret_cast<const f16x8*>(Sb1 + bbase + j * 512);
        #pragma unroll
        for (int i = 0; i < 4; i++)
            #pragma unroll
            for (int j = 0; j < 4; j++)
                acc[i][j] = __builtin_amdgcn_mfma_f32_16x16x32_f16(af[i], bf[j], acc[i][j], 0, 0, 0);
        #pragma unroll
        for (int i = 0; i < 4; i++)
            af[i] = *reinterpret_cast<const f16x8*>(Sa1 + abase + (4 + i) * 512);
        #pragma unroll
        for (int i = 0; i < 4; i++)
            #pragma unroll
            for (int j = 0; j < 4; j++)
                acc[4 + i][j] = __builtin_amdgcn_mfma_f32_16x16x32_f16(af[i], bf[j], acc[4 + i][j], 0, 0, 0);
    }
#undef STG_A
#undef STG_B
#undef SYNC_PT

    // epilogue: bias + route. q/k: [b][h][s][d]; v: [b][h][d][s] packed x4
    #pragma unroll
    for (int j = 0; j < 4; j++) {
        int m   = m0 + wn + j * 16 + lrow;
        int sec = m >> 10;
        int hd  = m & 1023;
        int hh  = hd >> 6, d = hd & 63;
        float bb = bias[m];
        if (sec == 2) {
            #pragma unroll
            for (int i = 0; i < 8; i++) {
                int n = n0 + G * 128 + i * 16 + quad * 4;   // r=0 element
                int bidx = n >> 11, s = n & 2047;
                f16x4 o;
                #pragma unroll
                for (int r = 0; r < 4; r++) o[r] = (f16)(acc[i][j][r] + bb);
                *reinterpret_cast<f16x4*>(
                    &vTo[(((size_t)(bidx * H_ + hh)) * DH_ + d) * S_ + s]) = o;
            }
        } else {
            f16* dst = (sec == 0) ? qo : ko;
            float sc = (sec == 0) ? QSC_ : 1.0f;
            #pragma unroll
            for (int i = 0; i < 8; i++) {
                #pragma unroll
                for (int r = 0; r < 4; r++) {
                    int n = n0 + G * 128 + i * 16 + quad * 4 + r;
                    int bidx = n >> 11, s = n & 2047;
                    dst[(((size_t)(bidx * H_ + hh)) * S_ + s) * DH_ + d] =
                        (f16)((acc[i][j][r] + bb) * sc);
                }
            }
        }
    }
}

// --------------------------------------------------------------- flash attention
// v5 (R3, 76.4us): 128 q rows/block, 64-KV tiles double-buffered via
// global_load_lds with source-side XOR swizzles (0 bank conflicts), 4 blocks/CU,
// intra-tile software pipeline + s_setprio.
// q,k: [bh][s][64] (q pre-scaled by QSC_); vT: [bh][64][s]; ctx: [b*S][1024] f16
__global__ __launch_bounds__(256, 4) void attn_kernel(
        const f16* __restrict__ q, const f16* __restrict__ k,
        const f16* __restrict__ vT, f16* __restrict__ ctx) {
    __shared__ __align__(16) f16 Ks[2][64 * 64];   // [slot][d], swizzled parts
    __shared__ __align__(16) f16 Vs[2][64 * 64];   // [d][kv],  swizzled parts
    const int tid  = threadIdx.x;
    const int lane = tid & 63, w = tid >> 6;
    const int quad = lane >> 4, lrow = lane & 15;
    const int id = blockIdx.x;
    const int bh = id & 63;                  // id%8 == bh%8 -> same XCD per head
    const int q0 = (id >> 6) * 128;          // 128 q rows per block, 32 per wave
    const int b  = bh >> 4, h = bh & 15;
    const f16* qb = q  + (size_t)bh * S_ * DH_;
    const f16* kb = k  + (size_t)bh * S_ * DH_;
    const f16* vb = vT + (size_t)bh * DH_ * S_;

    // Q fragments (B-operand: n=lane&15 -> q, k=quad*8+j -> d); 2 frags/wave
    f16x8 qf[2][2];
    #pragma unroll
    for (int f = 0; f < 2; f++)
        #pragma unroll
        for (int hf = 0; hf < 2; hf++)
            qf[f][hf] = *reinterpret_cast<const f16x8*>(
                qb + (size_t)(q0 + w * 32 + f * 16 + lrow) * DH_ + hf * 32 + quad * 8);

    // ones fragment for l-accumulation MFMA (A[m][k] = 1)
    f16x8 ones8;
    #pragma unroll
    for (int i = 0; i < 8; i++) ones8[i] = (f16)1.f;

    f32x4 lacc[2];    // all 16 C-rows hold the same full kv-sum per q-col
    f32x4 ot[2][4];   // O^T accum: col=lane&15 -> q, row=dj*16+quad*4+r -> d
    #pragma unroll
    for (int f = 0; f < 2; f++) {
        lacc[f] = {0.f, 0.f, 0.f, 0.f};
        #pragma unroll
        for (int dj = 0; dj < 4; dj++) ot[f][dj] = {0.f, 0.f, 0.f, 0.f};
    }

    // K gl16 source offsets: chunk c -> LDS slot s=c>>3, 16B part p=c&7.
    // Stored data = K[ sigma^{-1}(s) ][ (p ^ (s&7))*8 .. +8 ).
    // sigma^{-1}: s -> (s&~31) | (((s>>2)&3)<<3) | (((s>>4)&1)<<2) | (s&3)
    // V gl16 source offsets: chunk c -> LDS row d=c>>3, part p=c&7 stores
    // kv-part p^(d&7) of global row d.
    int koff[2], voff[2];
    #pragma unroll
    for (int i = 0; i < 2; i++) {
        int c = i * 256 + tid;
        int s = c >> 3, p = c & 7;
        int g = (s & ~31) | (((s >> 2) & 3) << 3) | (((s >> 4) & 1) << 2) | (s & 3);
        koff[i] = g * DH_ + ((p ^ (s & 7)) * 8);
        voff[i] = s * S_ + ((p ^ (s & 7)) * 8);   // for V: s is the d-row
    }

    // stage tile 0 into buf 0
    #pragma unroll
    for (int i = 0; i < 2; i++) {
        gl16(kb + koff[i], &Ks[0][(i * 256 + tid) * 8]);
        gl16(vb + voff[i], &Vs[0][(i * 256 + tid) * 8]);
    }
    __syncthreads();

    // read-side XOR chunk offsets (elements) for K
    const int xr0 = (quad ^ (lrow & 7)) * 8;          // d-part quad
    const int xr1 = ((quad + 4) ^ (lrow & 7)) * 8;    // d-part quad+4

    union PU { f16x8 v; f16x2 w[4]; };

    const int NT = S_ / 64;
    for (int kt = 0; kt < NT; kt++) {
        const int cur = kt & 1;
        const f16* Kc = Ks[cur];
        const f16* Vc = Vs[cur];

        // ---- QK strips 0,1 (t=0)
        f32x4 st0[2][2];
        __builtin_amdgcn_s_setprio(1);
        #pragma unroll
        for (int half = 0; half < 2; half++) {
            const int rb = (half * 16 + lrow) * 64;
            const f16x8 k0 = *reinterpret_cast<const f16x8*>(&Kc[rb + xr0]);
            const f16x8 k1 = *reinterpret_cast<const f16x8*>(&Kc[rb + xr1]);
            #pragma unroll
            for (int f = 0; f < 2; f++) {
                f32x4 s = {0.f, 0.f, 0.f, 0.f};
                s = __builtin_amdgcn_mfma_f32_16x16x32_f16(k0, qf[f][0], s, 0, 0, 0);
                s = __builtin_amdgcn_mfma_f32_16x16x32_f16(k1, qf[f][1], s, 0, 0, 0);
                st0[half][f] = s;
            }
        }
        __builtin_amdgcn_s_setprio(0);

        // ---- issue next tile staging (lands during this tile's compute)
        if (kt + 1 < NT) {
            const size_t kv1 = (size_t)(kt + 1) * 64;
            #pragma unroll
            for (int i = 0; i < 2; i++) {
                gl16(kb + kv1 * DH_ + koff[i], &Ks[cur ^ 1][(i * 256 + tid) * 8]);
                gl16(vb + kv1 + voff[i],       &Vs[cur ^ 1][(i * 256 + tid) * 8]);
            }
        }

        // ---- exp + pack t=0
        PU p0[2];
        #pragma unroll
        for (int half = 0; half < 2; half++)
            #pragma unroll
            for (int f = 0; f < 2; f++) {
                f16x2 lo = pk_cvt(__builtin_amdgcn_exp2f(st0[half][f][0]),
                                  __builtin_amdgcn_exp2f(st0[half][f][1]));
                f16x2 hi = pk_cvt(__builtin_amdgcn_exp2f(st0[half][f][2]),
                                  __builtin_amdgcn_exp2f(st0[half][f][3]));
                p0[f].w[half * 2 + 0] = lo;
                p0[f].w[half * 2 + 1] = hi;
            }

        // ---- QK strips 2,3 (t=1) — bridges exp(t0)->PV(t0) dependency gap
        f32x4 st1[2][2];
        __builtin_amdgcn_s_setprio(1);
        #pragma unroll
        for (int half = 0; half < 2; half++) {
            const int rb = ((2 + half) * 16 + lrow) * 64;
            const f16x8 k0 = *reinterpret_cast<const f16x8*>(&Kc[rb + xr0]);
            const f16x8 k1 = *reinterpret_cast<const f16x8*>(&Kc[rb + xr1]);
            #pragma unroll
            for (int f = 0; f < 2; f++) {
                f32x4 s = {0.f, 0.f, 0.f, 0.f};
                s = __builtin_amdgcn_mfma_f32_16x16x32_f16(k0, qf[f][0], s, 0, 0, 0);
                s = __builtin_amdgcn_mfma_f32_16x16x32_f16(k1, qf[f][1], s, 0, 0, 0);
                st1[half][f] = s;
            }
        }
        __builtin_amdgcn_s_setprio(0);

        // ---- V fragments t=0
        f16x8 vf0[4];
        #pragma unroll
        for (int dj = 0; dj < 4; dj++)
            vf0[dj] = *reinterpret_cast<const f16x8*>(
                &Vc[(dj * 16 + lrow) * 64 + ((quad ^ (lrow & 7)) * 8)]);

        // ---- PV t=0 + lacc0
        __builtin_amdgcn_s_setprio(1);
        #pragma unroll
        for (int dj = 0; dj < 4; dj++)
            #pragma unroll
            for (int f = 0; f < 2; f++)
                ot[f][dj] = __builtin_amdgcn_mfma_f32_16x16x32_f16(vf0[dj], p0[f].v, ot[f][dj], 0, 0, 0);
        #pragma unroll
        for (int f = 0; f < 2; f++)
            lacc[f] = __builtin_amdgcn_mfma_f32_16x16x32_f16(ones8, p0[f].v, lacc[f], 0, 0, 0);
        __builtin_amdgcn_s_setprio(0);

        // ---- exp + pack t=1
        PU p1[2];
        #pragma unroll
        for (int half = 0; half < 2; half++)
            #pragma unroll
            for (int f = 0; f < 2; f++) {
                f16x2 lo = pk_cvt(__builtin_amdgcn_exp2f(st1[half][f][0]),
                                  __builtin_amdgcn_exp2f(st1[half][f][1]));
                f16x2 hi = pk_cvt(__builtin_amdgcn_exp2f(st1[half][f][2]),
                                  __builtin_amdgcn_exp2f(st1[half][f][3]));
                p1[f].w[half * 2 + 0] = lo;
                p1[f].w[half * 2 + 1] = hi;
            }

        // ---- V fragments t=1
        f16x8 vf1[4];
        #pragma unroll
        for (int dj = 0; dj < 4; dj++)
            vf1[dj] = *reinterpret_cast<const f16x8*>(
                &Vc[(dj * 16 + lrow) * 64 + (((4 + quad) ^ (lrow & 7)) * 8)]);

        // ---- PV t=1 + lacc1
        __builtin_amdgcn_s_setprio(1);
        #pragma unroll
        for (int dj = 0; dj < 4; dj++)
            #pragma unroll
            for (int f = 0; f < 2; f++)
                ot[f][dj] = __builtin_amdgcn_mfma_f32_16x16x32_f16(vf1[dj], p1[f].v, ot[f][dj], 0, 0, 0);
        #pragma unroll
        for (int f = 0; f < 2; f++)
            lacc[f] = __builtin_amdgcn_mfma_f32_16x16x32_f16(ones8, p1[f].v, lacc[f], 0, 0, 0);
        __builtin_amdgcn_s_setprio(0);

        __syncthreads();   // drains gl16 (vmcnt) -> next buffer ready
    }

    #pragma unroll
    for (int f = 0; f < 2; f++) {
        float inv = 1.0f / lacc[f][0];
        int qrow = q0 + w * 32 + f * 16 + lrow;
        #pragma unroll
        for (int dj = 0; dj < 4; dj++) {
            f16x4 o;
            #pragma unroll
            for (int r = 0; r < 4; r++) o[r] = (f16)(ot[f][dj][r] * inv);
            *reinterpret_cast<f16x4*>(
                &ctx[((size_t)(b * S_ + qrow)) * D_ + h * DH_ + dj * 16 + quad * 4]) = o;
        }
    }
}

// --------------------------------------------------------------- output GEMM
// out[n][m] = sum_k ctx[n][k]*Bt[m][k] + bias[m]   (fp32 out)
__global__ __launch_bounds__(256) void gemm_out_kernel(
        const f16* __restrict__ A, const f16* __restrict__ Bt,
        const float* __restrict__ bias, float* __restrict__ out) {
    __shared__ __align__(16) f16 As[128 * 32];
    __shared__ __align__(16) f16 Bs[128 * 32];
    const int tid  = threadIdx.x;
    const int lane = tid & 63, w = tid >> 6;
    const int quad = lane >> 4, lrow = lane & 15;
    const int wm = (w & 1) * 64, wn = (w >> 1) * 64;
    const int n0 = blockIdx.x * 128, m0 = blockIdx.y * 128;

    f32x4 acc[4][4];
    #pragma unroll
    for (int i = 0; i < 4; i++)
        #pragma unroll
        for (int j = 0; j < 4; j++) acc[i][j] = {0.f, 0.f, 0.f, 0.f};

    const int ar0 = tid >> 2, ap0 = tid & 3;
    const f16* Ag0 = A  + (size_t)(n0 + ar0) * D_ + ap0 * 8;
    const f16* Ag1 = Ag0 + (size_t)64 * D_;
    const f16* Bg0 = Bt + (size_t)(m0 + ar0) * D_ + ap0 * 8;
    const f16* Bg1 = Bg0 + (size_t)64 * D_;
    f16* Asl = As + tid * 8;
    f16* Bsl = Bs + tid * 8;

    for (int kt = 0; kt < D_ / 32; kt++) {
        gl16(Ag0 + kt * 32, Asl);
        gl16(Ag1 + kt * 32, Asl + 64 * 32);
        gl16(Bg0 + kt * 32, Bsl);
        gl16(Bg1 + kt * 32, Bsl + 64 * 32);
        __syncthreads();
        f16x8 af[4], bf[4];
        #pragma unroll
        for (int i = 0; i < 4; i++)
            af[i] = *reinterpret_cast<const f16x8*>(&As[(wm + i * 16 + lrow) * 32 + quad * 8]);
        #pragma unroll
        for (int j = 0; j < 4; j++)
            bf[j] = *reinterpret_cast<const f16x8*>(&Bs[(wn + j * 16 + lrow) * 32 + quad * 8]);
        #pragma unroll
        for (int i = 0; i < 4; i++)
            #pragma unroll
            for (int j = 0; j < 4; j++)
                acc[i][j] = __builtin_amdgcn_mfma_f32_16x16x32_f16(af[i], bf[j], acc[i][j], 0, 0, 0);
        __syncthreads();
    }

    #pragma unroll
    for (int j = 0; j < 4; j++) {
        int m = m0 + wn + j * 16 + lrow;
        float bb = bias[m];
        #pragma unroll
        for (int i = 0; i < 4; i++)
            #pragma unroll
            for (int r = 0; r < 4; r++) {
                int n = n0 + wm + i * 16 + quad * 4 + r;
                out[(size_t)n * D_ + m] = acc[i][j][r] + bb;
            }
    }
}

// ------------------------------------------------------------------- launcher
extern "C" void kernel_launch(void* const* d_in, const int* in_sizes, int n_in,
                              void* d_out, int out_size, void* d_ws, size_t ws_size,
                              hipStream_t stream) {
    (void)in_sizes; (void)n_in; (void)out_size; (void)ws_size;
    const float* x     = (const float*)d_in[0];
    const float* w_qkv = (const float*)d_in[1];
    const float* b_qkv = (const float*)d_in[2];
    const float* w_out = (const float*)d_in[3];
    const float* b_out = (const float*)d_in[4];
    float* out = (float*)d_out;

    char* ws = (char*)d_ws;
    const size_t MB = 1024 * 1024;
    f16* xb    = (f16*)(ws);             // 16 MB  (reused as ctx after GEMM1)
    f16* wqkvT = (f16*)(ws + 16 * MB);   // 6 MB
    f16* woutT = (f16*)(ws + 22 * MB);   // 2 MB
    f16* qs    = (f16*)(ws + 24 * MB);   // 16 MB  [b][h][s][d], pre-scaled
    f16* kk    = (f16*)(ws + 40 * MB);   // 16 MB  [b][h][s][d]
    f16* vTb   = (f16*)(ws + 72 * MB);   // 16 MB  [b][h][d][s] (written by gemm_qkv)
    f16* ctx   = xb;                     // alias: xb dead after gemm_qkv

    cvt_x_kernel<<<(N_ * D_) / (256 * 4), 256, 0, stream>>>(x, xb);
    wt_cvt_kernel<<<dim3(M3_ / 32, D_ / 32), 256, 0, stream>>>(w_qkv, wqkvT, D_, M3_);
    wt_cvt_kernel<<<dim3(D_ / 32, D_ / 32), 256, 0, stream>>>(w_out, woutT, D_, D_);
    gemm_qkv_kernel<<<dim3((N_ / 256) * (M3_ / 256)), 512, 0, stream>>>(xb, wqkvT, b_qkv, qs, kk, vTb);
    attn_kernel<<<(B_ * H_) * (S_ / 128), 256, 0, stream>>>(qs, kk, vTb, ctx);
    gemm_out_kernel<<<dim3(N_ / 128, D_ / 128), 256, 0, stream>>>(ctx, woutT, b_out, out);
}